// Round 1
// baseline (262.772 us; speedup 1.0000x reference)
//
#include <hip/hip_runtime.h>
#include <math.h>

// BDH recurrence, parallelized:
//   xu = relu(emb @ Dx^T)                       (B,T,n)   GEMM
//   S_t = sum_n xu ; c_t scalar scan            (B,T)
//   x_t = (0.97 x_{t-1} + xu_t)/c_t             (B,T,n)   per-column scan
//   W[t,s] = (s<t) 0.97^(t-1-s) * (x_t . x_s)   (B,T,T)   GEMM + mask
//   a = W @ lnv,  lnv = LN(emb)                 (B,T,d)   GEMM
//   y = relu(LN(a) @ Dy^T) * x                  (B,T,n)   GEMM
//   out = LN(y @ E^T)                           (B,T,d)   GEMM + LN

#define TT 256      // T
#define BB 8        // B
#define DD 256      // d
#define NN 1024     // n
#define ROWS (BB*TT)   // 2048

// ---------------- LayerNorm over last dim = 256, one wave per row ----------
__launch_bounds__(256)
__global__ void ln_rows_kernel(const float* __restrict__ in, float* __restrict__ out,
                               int nrows) {
    int wave = threadIdx.x >> 6;
    int lane = threadIdx.x & 63;
    int row  = blockIdx.x * 4 + wave;
    if (row >= nrows) return;
    const float* p = in + (size_t)row * DD;
    float4 v = *(const float4*)(p + lane * 4);
    float s  = v.x + v.y + v.z + v.w;
    float s2 = v.x*v.x + v.y*v.y + v.z*v.z + v.w*v.w;
#pragma unroll
    for (int o = 32; o; o >>= 1) {
        s  += __shfl_xor(s,  o, 64);
        s2 += __shfl_xor(s2, o, 64);
    }
    float m   = s * (1.0f / 256.0f);
    float var = s2 * (1.0f / 256.0f) - m * m;
    float sc  = rsqrtf(var + 1e-5f);
    float4 o4;
    o4.x = (v.x - m) * sc;
    o4.y = (v.y - m) * sc;
    o4.z = (v.z - m) * sc;
    o4.w = (v.w - m) * sc;
    *(float4*)(out + (size_t)row * DD + lane * 4) = o4;
}

// ---------------- row sums of xu (rows of length 1024), one wave per row ---
__launch_bounds__(256)
__global__ void rowsum_kernel(const float* __restrict__ xu, float* __restrict__ S,
                              int nrows) {
    int wave = threadIdx.x >> 6;
    int lane = threadIdx.x & 63;
    int row  = blockIdx.x * 4 + wave;
    if (row >= nrows) return;
    const float* p = xu + (size_t)row * NN;
    float s = 0.f;
#pragma unroll
    for (int w = 0; w < 4; ++w) {
        float4 v = *(const float4*)(p + w * 256 + lane * 4);
        s += v.x + v.y + v.z + v.w;
    }
#pragma unroll
    for (int o = 32; o; o >>= 1) s += __shfl_xor(s, o, 64);
    if (lane == 0) S[row] = s;
}

// ---------------- scalar normalizer scan (exact recurrence) ----------------
__launch_bounds__(64)
__global__ void cscan_kernel(const float* __restrict__ S, float* __restrict__ c) {
    int b = threadIdx.x;
    if (b >= BB) return;
    float sigma = 0.f;                       // sum of normalized x_{t-1}
    for (int t = 0; t < TT; ++t) {
        float us = 0.97f * sigma + S[b * TT + t];
        float cc = fmaxf(us, 1e-12f);
        c[b * TT + t] = cc;
        sigma = us / cc;
    }
}

// ---------------- x scan: per (b, n) column over t --------------------------
__launch_bounds__(256)
__global__ void xscan_kernel(const float* __restrict__ xu, const float* __restrict__ c,
                             float* __restrict__ x) {
    int g = blockIdx.x * blockDim.x + threadIdx.x;   // 0 .. B*n-1
    int b = g >> 10;
    int j = g & (NN - 1);
    const float* xup = xu + (size_t)b * TT * NN + j;
    float*       xp  = x  + (size_t)b * TT * NN + j;
    const float* cp  = c + b * TT;
    float xs = 0.f;
    for (int t = 0; t < TT; ++t) {
        float u = 0.97f * xs + xup[(size_t)t * NN];
        xs = u / cp[t];
        xp[(size_t)t * NN] = xs;
    }
}

// ---------------- generic f32 NT GEMM: C[i,j] = sum_k A[i,k]*B[j,k] --------
// 64x64 tile, Ktile=16, 256 threads, 4x4 per thread.
// EPI: 0 = none, 1 = relu, 2 = relu then * Mul[i,j]
template <int EPI>
__launch_bounds__(256)
__global__ void gemm_nt_kernel(const float* __restrict__ A, const float* __restrict__ B,
                               float* __restrict__ C, const float* __restrict__ Mul,
                               int M, int N, int K) {
    __shared__ float As[16][68];
    __shared__ float Bs[16][68];
    const int t  = threadIdx.x;
    const int tx = t & 15, ty = t >> 4;
    const int i0 = blockIdx.y * 64, j0 = blockIdx.x * 64;
    const int r  = t >> 2, kq = t & 3;
    float acc[4][4] = {};
    for (int k0 = 0; k0 < K; k0 += 16) {
        float4 av = *(const float4*)(A + (size_t)(i0 + r) * K + k0 + kq * 4);
        float4 bv = *(const float4*)(B + (size_t)(j0 + r) * K + k0 + kq * 4);
        As[kq*4+0][r] = av.x; As[kq*4+1][r] = av.y; As[kq*4+2][r] = av.z; As[kq*4+3][r] = av.w;
        Bs[kq*4+0][r] = bv.x; Bs[kq*4+1][r] = bv.y; Bs[kq*4+2][r] = bv.z; Bs[kq*4+3][r] = bv.w;
        __syncthreads();
#pragma unroll
        for (int k = 0; k < 16; ++k) {
            float a0[4], b0[4];
#pragma unroll
            for (int u = 0; u < 4; ++u) { a0[u] = As[k][ty*4+u]; b0[u] = Bs[k][tx*4+u]; }
#pragma unroll
            for (int ii = 0; ii < 4; ++ii)
#pragma unroll
                for (int jj = 0; jj < 4; ++jj)
                    acc[ii][jj] = fmaf(a0[ii], b0[jj], acc[ii][jj]);
        }
        __syncthreads();
    }
#pragma unroll
    for (int ii = 0; ii < 4; ++ii) {
        int i = i0 + ty * 4 + ii;
        float4 o4;
        float vv[4];
#pragma unroll
        for (int jj = 0; jj < 4; ++jj) {
            float v = acc[ii][jj];
            if (EPI >= 1) v = fmaxf(v, 0.f);
            if (EPI == 2) v *= Mul[(size_t)i * N + j0 + tx * 4 + jj];
            vv[jj] = v;
        }
        o4.x = vv[0]; o4.y = vv[1]; o4.z = vv[2]; o4.w = vv[3];
        *(float4*)(C + (size_t)i * N + j0 + tx * 4) = o4;
    }
}

// ---------------- batched masked X X^T: W[b][t][s] -------------------------
__launch_bounds__(256)
__global__ void gemm_xxt_kernel(const float* __restrict__ x, float* __restrict__ Wm) {
    const int b  = blockIdx.z;
    const int t  = threadIdx.x;
    const int tx = t & 15, ty = t >> 4;
    const int i0 = blockIdx.y * 64;   // t index
    const int j0 = blockIdx.x * 64;   // s index
    float* W = Wm + (size_t)b * TT * TT;
    if (j0 > i0) {                    // fully masked tile: write zeros (ws is poisoned)
        float4 z = {0.f, 0.f, 0.f, 0.f};
#pragma unroll
        for (int ii = 0; ii < 4; ++ii)
            *(float4*)(W + (size_t)(i0 + ty * 4 + ii) * TT + j0 + tx * 4) = z;
        return;
    }
    const float* X = x + (size_t)b * TT * NN;
    __shared__ float As[16][68];
    __shared__ float Bs[16][68];
    const int r = t >> 2, kq = t & 3;
    float acc[4][4] = {};
    for (int k0 = 0; k0 < NN; k0 += 16) {
        float4 av = *(const float4*)(X + (size_t)(i0 + r) * NN + k0 + kq * 4);
        float4 bv = *(const float4*)(X + (size_t)(j0 + r) * NN + k0 + kq * 4);
        As[kq*4+0][r] = av.x; As[kq*4+1][r] = av.y; As[kq*4+2][r] = av.z; As[kq*4+3][r] = av.w;
        Bs[kq*4+0][r] = bv.x; Bs[kq*4+1][r] = bv.y; Bs[kq*4+2][r] = bv.z; Bs[kq*4+3][r] = bv.w;
        __syncthreads();
#pragma unroll
        for (int k = 0; k < 16; ++k) {
            float a0[4], b0[4];
#pragma unroll
            for (int u = 0; u < 4; ++u) { a0[u] = As[k][ty*4+u]; b0[u] = Bs[k][tx*4+u]; }
#pragma unroll
            for (int ii = 0; ii < 4; ++ii)
#pragma unroll
                for (int jj = 0; jj < 4; ++jj)
                    acc[ii][jj] = fmaf(a0[ii], b0[jj], acc[ii][jj]);
        }
        __syncthreads();
    }
    const float L2D = -0.043943348f;  // log2(0.97)
#pragma unroll
    for (int ii = 0; ii < 4; ++ii) {
        int ti = i0 + ty * 4 + ii;
        float vv[4];
#pragma unroll
        for (int jj = 0; jj < 4; ++jj) {
            int ss = j0 + tx * 4 + jj;
            float v = 0.f;
            if (ss < ti) v = exp2f((float)(ti - 1 - ss) * L2D) * acc[ii][jj];
            vv[jj] = v;
        }
        float4 o4 = {vv[0], vv[1], vv[2], vv[3]};
        *(float4*)(W + (size_t)ti * TT + j0 + tx * 4) = o4;
    }
}

// ---------------- batched NN GEMM: a[b] = W[b] @ lnv[b]  (256x256x256) -----
__launch_bounds__(256)
__global__ void gemm_nn_kernel(const float* __restrict__ Wm, const float* __restrict__ Bm,
                               float* __restrict__ Cm) {
    const int b = blockIdx.z;
    const float* A = Wm + (size_t)b * TT * TT;
    const float* B = Bm + (size_t)b * TT * DD;
    float*       C = Cm + (size_t)b * TT * DD;
    __shared__ float As[16][68];
    __shared__ float Bs[16][68];
    const int t  = threadIdx.x;
    const int tx = t & 15, ty = t >> 4;
    const int i0 = blockIdx.y * 64, j0 = blockIdx.x * 64;
    const int ra = t >> 2, kqa = t & 3;   // A tile load (NT-style over k)
    const int kb = t >> 4, jq  = t & 15;  // B tile load: row k, 64 j's
    float acc[4][4] = {};
    for (int k0 = 0; k0 < TT; k0 += 16) {
        float4 av = *(const float4*)(A + (size_t)(i0 + ra) * TT + k0 + kqa * 4);
        As[kqa*4+0][ra] = av.x; As[kqa*4+1][ra] = av.y; As[kqa*4+2][ra] = av.z; As[kqa*4+3][ra] = av.w;
        float4 bv = *(const float4*)(B + (size_t)(k0 + kb) * DD + j0 + jq * 4);
        *(float4*)&Bs[kb][jq * 4] = bv;
        __syncthreads();
#pragma unroll
        for (int k = 0; k < 16; ++k) {
            float a0[4], b0[4];
#pragma unroll
            for (int u = 0; u < 4; ++u) { a0[u] = As[k][ty*4+u]; b0[u] = Bs[k][tx*4+u]; }
#pragma unroll
            for (int ii = 0; ii < 4; ++ii)
#pragma unroll
                for (int jj = 0; jj < 4; ++jj)
                    acc[ii][jj] = fmaf(a0[ii], b0[jj], acc[ii][jj]);
        }
        __syncthreads();
    }
#pragma unroll
    for (int ii = 0; ii < 4; ++ii) {
        int i = i0 + ty * 4 + ii;
        float4 o4 = {acc[ii][0], acc[ii][1], acc[ii][2], acc[ii][3]};
        *(float4*)(C + (size_t)i * DD + j0 + tx * 4) = o4;
    }
}

extern "C" void kernel_launch(void* const* d_in, const int* in_sizes, int n_in,
                              void* d_out, int out_size, void* d_ws, size_t ws_size,
                              hipStream_t stream) {
    (void)in_sizes; (void)n_in; (void)out_size; (void)ws_size;
    const float* emb = (const float*)d_in[0];   // (B,T,d)
    const float* E   = (const float*)d_in[1];   // (d,n)
    const float* Dx  = (const float*)d_in[2];   // (n,d)
    const float* Dy  = (const float*)d_in[3];   // (n,d)
    float* out = (float*)d_out;                 // (B,T,d)

    float* ws = (float*)d_ws;
    size_t o = 0;
    float* lnv = ws + o; o += (size_t)ROWS * DD;   // LN(emb)
    float* xu  = ws + o; o += (size_t)ROWS * NN;   // relu(emb@Dx^T); reused as y
    float* S   = ws + o; o += ROWS;                // row sums
    float* c   = ws + o; o += ROWS;                // normalizers
    float* x   = ws + o; o += (size_t)ROWS * NN;   // x_t states
    float* W   = ws + o; o += (size_t)BB * TT * TT;
    float* a   = ws + o; o += (size_t)ROWS * DD;   // a_star; LN in-place
    float* v   = ws + o; o += (size_t)ROWS * DD;   // y@E^T

    // 1. lnv = LN(emb)
    ln_rows_kernel<<<ROWS / 4, 256, 0, stream>>>(emb, lnv, ROWS);
    // 2. xu = relu(emb @ Dx^T)   M=2048 N=1024 K=256
    gemm_nt_kernel<1><<<dim3(NN / 64, ROWS / 64), 256, 0, stream>>>(
        emb, Dx, xu, nullptr, ROWS, NN, DD);
    // 3. S = rowsum(xu)
    rowsum_kernel<<<ROWS / 4, 256, 0, stream>>>(xu, S, ROWS);
    // 4. c scan (scalar, exact)
    cscan_kernel<<<1, 64, 0, stream>>>(S, c);
    // 5. x scan (per column)
    xscan_kernel<<<(BB * NN) / 256, 256, 0, stream>>>(xu, c, x);
    // 6. W = mask . (X X^T)  batched
    gemm_xxt_kernel<<<dim3(TT / 64, TT / 64, BB), 256, 0, stream>>>(x, W);
    // 7. a = W @ lnv  batched
    gemm_nn_kernel<<<dim3(DD / 64, TT / 64, BB), 256, 0, stream>>>(W, lnv, a);
    // 8. LN(a) in-place
    ln_rows_kernel<<<ROWS / 4, 256, 0, stream>>>(a, a, ROWS);
    // 9. y = relu(a_ln @ Dy^T) * x   (into xu buffer)  M=2048 N=1024 K=256
    gemm_nt_kernel<2><<<dim3(NN / 64, ROWS / 64), 256, 0, stream>>>(
        a, Dy, xu, x, ROWS, NN, DD);
    // 10. v = y @ E^T   M=2048 N=256 K=1024
    gemm_nt_kernel<0><<<dim3(DD / 64, ROWS / 64), 256, 0, stream>>>(
        xu, E, v, nullptr, ROWS, DD, NN);
    // 11. out = LN(v)
    ln_rows_kernel<<<ROWS / 4, 256, 0, stream>>>(v, out, ROWS);
}

// Round 2
// 197.159 us; speedup vs baseline: 1.3328x; 1.3328x over previous
//
#include <hip/hip_runtime.h>
#include <math.h>

// BDH recurrence, parallelized:
//   xu = relu(emb @ Dx^T)                       (B,T,n)   GEMM
//   S_t = sum_n xu ; c_t scalar scan            (B,T)
//   x_t = (0.97 x_{t-1} + xu_t)/c_t             (B,T,n)   chunked affine scan
//   W[t,s] = (s<t) 0.97^(t-1-s) * (x_t . x_s)   (B,T,T)   GEMM + mask
//   a = W @ lnv,  lnv = LN(emb)                 (B,T,d)   GEMM
//   y = relu(LN(a) @ Dy^T) * x                  (B,T,n)   GEMM
//   out = LN(y @ E^T)                           (B,T,d)   GEMM + LN

#define TT 256      // T
#define BB 8        // B
#define DD 256      // d
#define NN 1024     // n
#define ROWS (BB*TT)   // 2048

// ---------------- LayerNorm over last dim = 256, one wave per row ----------
__launch_bounds__(256)
__global__ void ln_rows_kernel(const float* __restrict__ in, float* __restrict__ out,
                               int nrows) {
    int wave = threadIdx.x >> 6;
    int lane = threadIdx.x & 63;
    int row  = blockIdx.x * 4 + wave;
    if (row >= nrows) return;
    const float* p = in + (size_t)row * DD;
    float4 v = *(const float4*)(p + lane * 4);
    float s  = v.x + v.y + v.z + v.w;
    float s2 = v.x*v.x + v.y*v.y + v.z*v.z + v.w*v.w;
#pragma unroll
    for (int o = 32; o; o >>= 1) {
        s  += __shfl_xor(s,  o, 64);
        s2 += __shfl_xor(s2, o, 64);
    }
    float m   = s * (1.0f / 256.0f);
    float var = s2 * (1.0f / 256.0f) - m * m;
    float sc  = rsqrtf(var + 1e-5f);
    float4 o4;
    o4.x = (v.x - m) * sc;
    o4.y = (v.y - m) * sc;
    o4.z = (v.z - m) * sc;
    o4.w = (v.w - m) * sc;
    *(float4*)(out + (size_t)row * DD + lane * 4) = o4;
}

// ---------------- row sums of xu (rows of length 1024), one wave per row ---
__launch_bounds__(256)
__global__ void rowsum_kernel(const float* __restrict__ xu, float* __restrict__ S,
                              int nrows) {
    int wave = threadIdx.x >> 6;
    int lane = threadIdx.x & 63;
    int row  = blockIdx.x * 4 + wave;
    if (row >= nrows) return;
    const float* p = xu + (size_t)row * NN;
    float s = 0.f;
#pragma unroll
    for (int w = 0; w < 4; ++w) {
        float4 v = *(const float4*)(p + w * 256 + lane * 4);
        s += v.x + v.y + v.z + v.w;
    }
#pragma unroll
    for (int o = 32; o; o >>= 1) s += __shfl_xor(s, o, 64);
    if (lane == 0) S[row] = s;
}

// ---------------- scalar normalizer scan (exact recurrence) ----------------
// writes rc[b][t] = 1 / c_t
__launch_bounds__(64)
__global__ void cscan_kernel(const float* __restrict__ S, float* __restrict__ rc) {
    int b = threadIdx.x;
    if (b >= BB) return;
    float sigma = 0.f;                       // sum of normalized x_{t-1}
    for (int t = 0; t < TT; ++t) {
        float us = 0.97f * sigma + S[b * TT + t];
        float cc = fmaxf(us, 1e-12f);
        float r  = 1.0f / cc;
        rc[b * TT + t] = r;
        sigma = us * r;
    }
}

// ---------------- chunked x scan -------------------------------------------
// Block = 256 threads = 16 chunks x 16 columns; block handles (b, 16-col group).
// x_t = g_t * x_{t-1} + h_t with g_t = 0.97*rc_t, h_t = xu_t*rc_t.
// Phase A: per-chunk zero-carry scan -> (G = prod g, H = end value).
// Phase B: 16-step carry scan across chunks in LDS.
// Phase C: re-scan chunk with true carry, store x.  Exact up to f32 rounding.
__launch_bounds__(256)
__global__ void xscan_fused_kernel(const float* __restrict__ xu,
                                   const float* __restrict__ rc,
                                   float* __restrict__ x) {
    __shared__ float Gs[16][16], Hs[16][16], Cs[16][16];
    const int b    = blockIdx.x >> 6;          // 8 b * 64 jgrp
    const int jgrp = blockIdx.x & 63;
    const int tid  = threadIdx.x;
    const int ck   = tid >> 4;                 // chunk 0..15
    const int jl   = tid & 15;                 // column-in-group
    const int j    = jgrp * 16 + jl;
    const size_t base = ((size_t)b * TT + ck * 16) * NN + j;
    float xur[16], rcr[16];
#pragma unroll
    for (int i = 0; i < 16; ++i) xur[i] = xu[base + (size_t)i * NN];
#pragma unroll
    for (int i = 0; i < 16; ++i) rcr[i] = rc[b * TT + ck * 16 + i];
    float xs = 0.f, G = 1.f;
#pragma unroll
    for (int i = 0; i < 16; ++i) {
        xs = fmaf(0.97f, xs, xur[i]) * rcr[i];
        G *= 0.97f * rcr[i];
    }
    Gs[ck][jl] = G;
    Hs[ck][jl] = xs;
    __syncthreads();
    if (tid < 16) {                            // one thread per column
        float cr = 0.f;
        Cs[0][tid] = 0.f;
#pragma unroll
        for (int cc = 0; cc < 15; ++cc) {
            cr = fmaf(Gs[cc][tid], cr, Hs[cc][tid]);
            Cs[cc + 1][tid] = cr;
        }
    }
    __syncthreads();
    xs = Cs[ck][jl];
#pragma unroll
    for (int i = 0; i < 16; ++i) {
        xs = fmaf(0.97f, xs, xur[i]) * rcr[i];
        x[base + (size_t)i * NN] = xs;
    }
}

// ---------------- generic f32 NT GEMM: C[i,j] = sum_k A[i,k]*B[j,k] --------
// 64x64 tile, Ktile=16, 256 threads, 4x4 per thread.
// EPI: 0 = none, 1 = relu, 2 = relu then * Mul[i,j]
template <int EPI>
__launch_bounds__(256)
__global__ void gemm_nt_kernel(const float* __restrict__ A, const float* __restrict__ B,
                               float* __restrict__ C, const float* __restrict__ Mul,
                               int M, int N, int K) {
    __shared__ float As[16][68];
    __shared__ float Bs[16][68];
    const int t  = threadIdx.x;
    const int tx = t & 15, ty = t >> 4;
    const int i0 = blockIdx.y * 64, j0 = blockIdx.x * 64;
    const int r  = t >> 2, kq = t & 3;
    float acc[4][4] = {};
    for (int k0 = 0; k0 < K; k0 += 16) {
        float4 av = *(const float4*)(A + (size_t)(i0 + r) * K + k0 + kq * 4);
        float4 bv = *(const float4*)(B + (size_t)(j0 + r) * K + k0 + kq * 4);
        As[kq*4+0][r] = av.x; As[kq*4+1][r] = av.y; As[kq*4+2][r] = av.z; As[kq*4+3][r] = av.w;
        Bs[kq*4+0][r] = bv.x; Bs[kq*4+1][r] = bv.y; Bs[kq*4+2][r] = bv.z; Bs[kq*4+3][r] = bv.w;
        __syncthreads();
#pragma unroll
        for (int k = 0; k < 16; ++k) {
            float a0[4], b0[4];
#pragma unroll
            for (int u = 0; u < 4; ++u) { a0[u] = As[k][ty*4+u]; b0[u] = Bs[k][tx*4+u]; }
#pragma unroll
            for (int ii = 0; ii < 4; ++ii)
#pragma unroll
                for (int jj = 0; jj < 4; ++jj)
                    acc[ii][jj] = fmaf(a0[ii], b0[jj], acc[ii][jj]);
        }
        __syncthreads();
    }
#pragma unroll
    for (int ii = 0; ii < 4; ++ii) {
        int i = i0 + ty * 4 + ii;
        float4 o4;
        float vv[4];
#pragma unroll
        for (int jj = 0; jj < 4; ++jj) {
            float v = acc[ii][jj];
            if (EPI >= 1) v = fmaxf(v, 0.f);
            if (EPI == 2) v *= Mul[(size_t)i * N + j0 + tx * 4 + jj];
            vv[jj] = v;
        }
        o4.x = vv[0]; o4.y = vv[1]; o4.z = vv[2]; o4.w = vv[3];
        *(float4*)(C + (size_t)i * N + j0 + tx * 4) = o4;
    }
}

// ---------------- batched masked X X^T: W[b][t][s] -------------------------
__launch_bounds__(256)
__global__ void gemm_xxt_kernel(const float* __restrict__ x, float* __restrict__ Wm) {
    const int b  = blockIdx.z;
    const int t  = threadIdx.x;
    const int tx = t & 15, ty = t >> 4;
    const int i0 = blockIdx.y * 64;   // t index
    const int j0 = blockIdx.x * 64;   // s index
    float* W = Wm + (size_t)b * TT * TT;
    if (j0 > i0) {                    // fully masked tile: write zeros (ws is poisoned)
        float4 z = {0.f, 0.f, 0.f, 0.f};
#pragma unroll
        for (int ii = 0; ii < 4; ++ii)
            *(float4*)(W + (size_t)(i0 + ty * 4 + ii) * TT + j0 + tx * 4) = z;
        return;
    }
    const float* X = x + (size_t)b * TT * NN;
    __shared__ float As[16][68];
    __shared__ float Bs[16][68];
    const int r = t >> 2, kq = t & 3;
    float acc[4][4] = {};
    for (int k0 = 0; k0 < NN; k0 += 16) {
        float4 av = *(const float4*)(X + (size_t)(i0 + r) * NN + k0 + kq * 4);
        float4 bv = *(const float4*)(X + (size_t)(j0 + r) * NN + k0 + kq * 4);
        As[kq*4+0][r] = av.x; As[kq*4+1][r] = av.y; As[kq*4+2][r] = av.z; As[kq*4+3][r] = av.w;
        Bs[kq*4+0][r] = bv.x; Bs[kq*4+1][r] = bv.y; Bs[kq*4+2][r] = bv.z; Bs[kq*4+3][r] = bv.w;
        __syncthreads();
#pragma unroll
        for (int k = 0; k < 16; ++k) {
            float a0[4], b0[4];
#pragma unroll
            for (int u = 0; u < 4; ++u) { a0[u] = As[k][ty*4+u]; b0[u] = Bs[k][tx*4+u]; }
#pragma unroll
            for (int ii = 0; ii < 4; ++ii)
#pragma unroll
                for (int jj = 0; jj < 4; ++jj)
                    acc[ii][jj] = fmaf(a0[ii], b0[jj], acc[ii][jj]);
        }
        __syncthreads();
    }
    const float L2D = -0.043943348f;  // log2(0.97)
#pragma unroll
    for (int ii = 0; ii < 4; ++ii) {
        int ti = i0 + ty * 4 + ii;
        float vv[4];
#pragma unroll
        for (int jj = 0; jj < 4; ++jj) {
            int ss = j0 + tx * 4 + jj;
            float v = 0.f;
            if (ss < ti) v = exp2f((float)(ti - 1 - ss) * L2D) * acc[ii][jj];
            vv[jj] = v;
        }
        float4 o4 = {vv[0], vv[1], vv[2], vv[3]};
        *(float4*)(W + (size_t)ti * TT + j0 + tx * 4) = o4;
    }
}

// ---------------- batched NN GEMM: a[b] = W[b] @ lnv[b]  (256x256x256) -----
__launch_bounds__(256)
__global__ void gemm_nn_kernel(const float* __restrict__ Wm, const float* __restrict__ Bm,
                               float* __restrict__ Cm) {
    const int b = blockIdx.z;
    const float* A = Wm + (size_t)b * TT * TT;
    const float* B = Bm + (size_t)b * TT * DD;
    float*       C = Cm + (size_t)b * TT * DD;
    __shared__ float As[16][68];
    __shared__ float Bs[16][68];
    const int t  = threadIdx.x;
    const int tx = t & 15, ty = t >> 4;
    const int i0 = blockIdx.y * 64, j0 = blockIdx.x * 64;
    const int ra = t >> 2, kqa = t & 3;   // A tile load (NT-style over k)
    const int kb = t >> 4, jq  = t & 15;  // B tile load: row k, 64 j's
    float acc[4][4] = {};
    for (int k0 = 0; k0 < TT; k0 += 16) {
        float4 av = *(const float4*)(A + (size_t)(i0 + ra) * TT + k0 + kqa * 4);
        As[kqa*4+0][ra] = av.x; As[kqa*4+1][ra] = av.y; As[kqa*4+2][ra] = av.z; As[kqa*4+3][ra] = av.w;
        float4 bv = *(const float4*)(B + (size_t)(k0 + kb) * DD + j0 + jq * 4);
        *(float4*)&Bs[kb][jq * 4] = bv;
        __syncthreads();
#pragma unroll
        for (int k = 0; k < 16; ++k) {
            float a0[4], b0[4];
#pragma unroll
            for (int u = 0; u < 4; ++u) { a0[u] = As[k][ty*4+u]; b0[u] = Bs[k][tx*4+u]; }
#pragma unroll
            for (int ii = 0; ii < 4; ++ii)
#pragma unroll
                for (int jj = 0; jj < 4; ++jj)
                    acc[ii][jj] = fmaf(a0[ii], b0[jj], acc[ii][jj]);
        }
        __syncthreads();
    }
#pragma unroll
    for (int ii = 0; ii < 4; ++ii) {
        int i = i0 + ty * 4 + ii;
        float4 o4 = {acc[ii][0], acc[ii][1], acc[ii][2], acc[ii][3]};
        *(float4*)(C + (size_t)i * DD + j0 + tx * 4) = o4;
    }
}

extern "C" void kernel_launch(void* const* d_in, const int* in_sizes, int n_in,
                              void* d_out, int out_size, void* d_ws, size_t ws_size,
                              hipStream_t stream) {
    (void)in_sizes; (void)n_in; (void)out_size; (void)ws_size;
    const float* emb = (const float*)d_in[0];   // (B,T,d)
    const float* E   = (const float*)d_in[1];   // (d,n)
    const float* Dx  = (const float*)d_in[2];   // (n,d)
    const float* Dy  = (const float*)d_in[3];   // (n,d)
    float* out = (float*)d_out;                 // (B,T,d)

    float* ws = (float*)d_ws;
    size_t o = 0;
    float* lnv = ws + o; o += (size_t)ROWS * DD;   // LN(emb)
    float* xu  = ws + o; o += (size_t)ROWS * NN;   // relu(emb@Dx^T); reused as y
    float* S   = ws + o; o += ROWS;                // row sums
    float* rc  = ws + o; o += ROWS;                // 1/c normalizers
    float* x   = ws + o; o += (size_t)ROWS * NN;   // x_t states
    float* W   = ws + o; o += (size_t)BB * TT * TT;
    float* a   = ws + o; o += (size_t)ROWS * DD;   // a_star; LN in-place
    float* v   = ws + o; o += (size_t)ROWS * DD;   // y@E^T

    // 1. lnv = LN(emb)
    ln_rows_kernel<<<ROWS / 4, 256, 0, stream>>>(emb, lnv, ROWS);
    // 2. xu = relu(emb @ Dx^T)   M=2048 N=1024 K=256
    gemm_nt_kernel<1><<<dim3(NN / 64, ROWS / 64), 256, 0, stream>>>(
        emb, Dx, xu, nullptr, ROWS, NN, DD);
    // 3. S = rowsum(xu)
    rowsum_kernel<<<ROWS / 4, 256, 0, stream>>>(xu, S, ROWS);
    // 4. c scan (scalar, exact) -> reciprocals
    cscan_kernel<<<1, 64, 0, stream>>>(S, rc);
    // 5. x scan, chunked 16x16 per block
    xscan_fused_kernel<<<BB * (NN / 16), 256, 0, stream>>>(xu, rc, x);
    // 6. W = mask . (X X^T)  batched
    gemm_xxt_kernel<<<dim3(TT / 64, TT / 64, BB), 256, 0, stream>>>(x, W);
    // 7. a = W @ lnv  batched
    gemm_nn_kernel<<<dim3(DD / 64, TT / 64, BB), 256, 0, stream>>>(W, lnv, a);
    // 8. LN(a) in-place
    ln_rows_kernel<<<ROWS / 4, 256, 0, stream>>>(a, a, ROWS);
    // 9. y = relu(a_ln @ Dy^T) * x   (into xu buffer)  M=2048 N=1024 K=256
    gemm_nt_kernel<2><<<dim3(NN / 64, ROWS / 64), 256, 0, stream>>>(
        a, Dy, xu, x, ROWS, NN, DD);
    // 10. v = y @ E^T   M=2048 N=256 K=1024
    gemm_nt_kernel<0><<<dim3(DD / 64, ROWS / 64), 256, 0, stream>>>(
        xu, E, v, nullptr, ROWS, DD, NN);
    // 11. out = LN(v)
    ln_rows_kernel<<<ROWS / 4, 256, 0, stream>>>(v, out, ROWS);
}

// Round 4
// 125.377 us; speedup vs baseline: 2.0959x; 1.5725x over previous
//
#include <hip/hip_runtime.h>
#include <math.h>

// BDH recurrence, parallelized + MFMA (split-bf16 hi/lo = f32-accuracy GEMMs):
//   xu = relu(emb @ Dx^T)                       MFMA GEMM (f32 out)
//   S_t = rowsum ; c_t scalar scan ; x chunked affine scan (split-bf16 x out)
//   W[t,s] = (s<t) 0.97^(t-1-s) * (x_t . x_s)   MFMA GEMM + mask (split out)
//   a = W @ lnvT^T                              MFMA GEMM (f32 out)
//   y = relu(LN(a) @ Dy^T) * x                  MFMA GEMM (split out)
//   out = LN(y @ E^T)                           MFMA GEMM + LN

#define TT 256
#define BB 8
#define DD 256
#define NN 1024
#define ROWS (BB*TT)   // 2048

typedef unsigned short U16;
using s16x8 = __attribute__((ext_vector_type(8))) short;
using u16x8 = __attribute__((ext_vector_type(8))) unsigned short;
using u16x4 = __attribute__((ext_vector_type(4))) unsigned short;
using f32x4 = __attribute__((ext_vector_type(4))) float;

__device__ inline U16 bf16h(float f) {
    unsigned int u = __builtin_bit_cast(unsigned int, f);
    u += 0x7FFFu + ((u >> 16) & 1u);
    return (U16)(u >> 16);
}
__device__ inline float b2f(U16 h) {
    return __builtin_bit_cast(float, (unsigned int)h << 16);
}
// returns hi in bits [15:0], lo in bits [31:16]
__device__ inline unsigned int split2(float f) {
    U16 h = bf16h(f);
    U16 l = bf16h(f - b2f(h));
    return (unsigned int)h | ((unsigned int)l << 16);
}
__device__ inline f32x4 mfma16(s16x8 a, s16x8 b, f32x4 c) {
    return __builtin_amdgcn_mfma_f32_16x16x32_bf16(a, b, c, 0, 0, 0);
}

// ---------------- convert the 4 f32 inputs to split bf16 -------------------
__launch_bounds__(256)
__global__ void cvt_kernel(const float* __restrict__ e0, const float* __restrict__ e1,
                           const float* __restrict__ e2, const float* __restrict__ e3,
                           U16* h0, U16* l0, U16* h1, U16* l1,
                           U16* h2, U16* l2, U16* h3, U16* l3) {
    int base = (blockIdx.x * 256 + threadIdx.x) * 4;
    const float* s; U16 *dh, *dl; int loc;
    if      (base <  524288) { s = e0; dh = h0; dl = l0; loc = base; }
    else if (base <  786432) { s = e1; dh = h1; dl = l1; loc = base - 524288; }
    else if (base < 1048576) { s = e2; dh = h2; dl = l2; loc = base - 786432; }
    else                     { s = e3; dh = h3; dl = l3; loc = base - 1048576; }
    float4 v = *(const float4*)(s + loc);
    unsigned int p0 = split2(v.x), p1 = split2(v.y), p2 = split2(v.z), p3 = split2(v.w);
    u16x4 hh = {(U16)p0, (U16)p1, (U16)p2, (U16)p3};
    u16x4 ll = {(U16)(p0 >> 16), (U16)(p1 >> 16), (U16)(p2 >> 16), (U16)(p3 >> 16)};
    *(u16x4*)(dh + loc) = hh;
    *(u16x4*)(dl + loc) = ll;
}

// ---------------- LayerNorm rows of 256 ------------------------------------
// MODE 0: f32 rows out.  MODE 1: split-bf16 rows out.
// MODE 2: split-bf16 TRANSPOSED out per batch: outT[b][j][t] (for W@lnv B-op).
template <int MODE>
__launch_bounds__(256)
__global__ void ln_kernel(const float* __restrict__ in, float* __restrict__ outf,
                          U16* __restrict__ outh, U16* __restrict__ outl) {
    int wave = threadIdx.x >> 6;
    int lane = threadIdx.x & 63;
    int row  = blockIdx.x * 4 + wave;
    const float* p = in + (size_t)row * DD;
    float4 v = *(const float4*)(p + lane * 4);
    float s  = v.x + v.y + v.z + v.w;
    float s2 = v.x*v.x + v.y*v.y + v.z*v.z + v.w*v.w;
#pragma unroll
    for (int o = 32; o; o >>= 1) {
        s  += __shfl_xor(s,  o, 64);
        s2 += __shfl_xor(s2, o, 64);
    }
    float m   = s * (1.0f / 256.0f);
    float var = s2 * (1.0f / 256.0f) - m * m;
    float sc  = rsqrtf(var + 1e-5f);
    float r4[4] = {(v.x - m) * sc, (v.y - m) * sc, (v.z - m) * sc, (v.w - m) * sc};
    if (MODE == 0) {
        float4 o4 = {r4[0], r4[1], r4[2], r4[3]};
        *(float4*)(outf + (size_t)row * DD + lane * 4) = o4;
    } else if (MODE == 1) {
        u16x4 hh, ll;
#pragma unroll
        for (int u = 0; u < 4; ++u) {
            unsigned int pp = split2(r4[u]);
            hh[u] = (U16)pp; ll[u] = (U16)(pp >> 16);
        }
        *(u16x4*)(outh + (size_t)row * DD + lane * 4) = hh;
        *(u16x4*)(outl + (size_t)row * DD + lane * 4) = ll;
    } else {
        int b = row >> 8, t = row & 255;
#pragma unroll
        for (int u = 0; u < 4; ++u) {
            int j = lane * 4 + u;
            size_t o = ((size_t)b * DD + j) * TT + t;
            unsigned int pp = split2(r4[u]);
            outh[o] = (U16)pp; outl[o] = (U16)(pp >> 16);
        }
    }
}

// ---------------- row sums of xu -------------------------------------------
__launch_bounds__(256)
__global__ void rowsum_kernel(const float* __restrict__ xu, float* __restrict__ S) {
    int wave = threadIdx.x >> 6;
    int lane = threadIdx.x & 63;
    int row  = blockIdx.x * 4 + wave;
    const float* p = xu + (size_t)row * NN;
    float s = 0.f;
#pragma unroll
    for (int w = 0; w < 4; ++w) {
        float4 v = *(const float4*)(p + w * 256 + lane * 4);
        s += v.x + v.y + v.z + v.w;
    }
#pragma unroll
    for (int o = 32; o; o >>= 1) s += __shfl_xor(s, o, 64);
    if (lane == 0) S[row] = s;
}

// ---------------- scalar normalizer scan -> reciprocals --------------------
__launch_bounds__(64)
__global__ void cscan_kernel(const float* __restrict__ S, float* __restrict__ rc) {
    int b = threadIdx.x;
    if (b >= BB) return;
    float sigma = 0.f;
    for (int t = 0; t < TT; ++t) {
        float us = 0.97f * sigma + S[b * TT + t];
        float cc = fmaxf(us, 1e-12f);
        float r  = 1.0f / cc;
        rc[b * TT + t] = r;
        sigma = us * r;
    }
}

// ---------------- chunked x scan; writes split-bf16 x ----------------------
__launch_bounds__(256)
__global__ void xscan_kernel(const float* __restrict__ xu, const float* __restrict__ rc,
                             U16* __restrict__ xh, U16* __restrict__ xl) {
    __shared__ float Gs[16][16], Hs[16][16], Cs[16][16];
    const int b    = blockIdx.x >> 6;
    const int jgrp = blockIdx.x & 63;
    const int tid  = threadIdx.x;
    const int ck   = tid >> 4;
    const int jl   = tid & 15;
    const int j    = jgrp * 16 + jl;
    const size_t base = ((size_t)b * TT + ck * 16) * NN + j;
    float xur[16], rcr[16];
#pragma unroll
    for (int i = 0; i < 16; ++i) xur[i] = xu[base + (size_t)i * NN];
#pragma unroll
    for (int i = 0; i < 16; ++i) rcr[i] = rc[b * TT + ck * 16 + i];
    float xs = 0.f, G = 1.f;
#pragma unroll
    for (int i = 0; i < 16; ++i) {
        xs = fmaf(0.97f, xs, xur[i]) * rcr[i];
        G *= 0.97f * rcr[i];
    }
    Gs[ck][jl] = G;
    Hs[ck][jl] = xs;
    __syncthreads();
    if (tid < 16) {
        float cr = 0.f;
        Cs[0][tid] = 0.f;
#pragma unroll
        for (int cc = 0; cc < 15; ++cc) {
            cr = fmaf(Gs[cc][tid], cr, Hs[cc][tid]);
            Cs[cc + 1][tid] = cr;
        }
    }
    __syncthreads();
    xs = Cs[ck][jl];
#pragma unroll
    for (int i = 0; i < 16; ++i) {
        xs = fmaf(0.97f, xs, xur[i]) * rcr[i];
        unsigned int pp = split2(xs);
        xh[base + (size_t)i * NN] = (U16)pp;
        xl[base + (size_t)i * NN] = (U16)(pp >> 16);
    }
}

// ---------------- split-bf16 MFMA NT GEMM ----------------------------------
// C[i,j] = sum_k A[i,k]*B[j,k], A/B given as bf16 hi/lo pairs ([rows][K]).
// 64x64 tile, 4 waves (each 32x32 = 2x2 16x16 frags), BK=32.
// EPI: 0 none->f32; 1 relu->f32; 2 relu*(Mulh+Mull)->split; 3 decay-mask->split.
template <int EPI>
__launch_bounds__(256)
__global__ void mfma_nt_kernel(const U16* __restrict__ Ah, const U16* __restrict__ Al,
                               const U16* __restrict__ Bh, const U16* __restrict__ Bl,
                               float* __restrict__ Cf, U16* __restrict__ Ch, U16* __restrict__ Cl,
                               const U16* __restrict__ Mulh, const U16* __restrict__ Mull,
                               int N, int K,
                               long long sA, long long sB, long long sC) {
    const int z = blockIdx.z;
    Ah += (size_t)z * sA; Al += (size_t)z * sA;
    Bh += (size_t)z * sB; Bl += (size_t)z * sB;
    if (EPI <= 1) { Cf += (size_t)z * sC; }
    else          { Ch += (size_t)z * sC; Cl += (size_t)z * sC; }
    const int i0 = blockIdx.y * 64, j0 = blockIdx.x * 64;
    const int t = threadIdx.x, lane = t & 63, wid = t >> 6;
    const int wr = wid >> 1, wc = wid & 1;
    const int lr = lane >> 4, lc = lane & 15;
    const float L2D = -0.043943348f;  // log2(0.97)

    if (EPI == 3 && j0 > i0) {        // fully-masked tile: zero-fill
#pragma unroll
        for (int fi = 0; fi < 2; ++fi)
#pragma unroll
            for (int fj = 0; fj < 2; ++fj)
#pragma unroll
                for (int r = 0; r < 4; ++r) {
                    int i = i0 + wr * 32 + fi * 16 + lr * 4 + r;
                    int j = j0 + wc * 32 + fj * 16 + lc;
                    size_t o = (size_t)i * N + j;
                    Ch[o] = 0; Cl[o] = 0;
                }
        return;
    }

    __shared__ __align__(16) U16 sAh[64][40], sAl[64][40], sBh[64][40], sBl[64][40];
    const int srow = t >> 2, skq = (t & 3) * 8;
    f32x4 acc[2][2];
    const f32x4 z4 = {0.f, 0.f, 0.f, 0.f};
    acc[0][0] = z4; acc[0][1] = z4; acc[1][0] = z4; acc[1][1] = z4;

    for (int k0 = 0; k0 < K; k0 += 32) {
        const size_t ga = (size_t)(i0 + srow) * K + k0 + skq;
        const size_t gb = (size_t)(j0 + srow) * K + k0 + skq;
        u16x8 va = *(const u16x8*)(Ah + ga);
        u16x8 vb = *(const u16x8*)(Al + ga);
        u16x8 vc = *(const u16x8*)(Bh + gb);
        u16x8 vd = *(const u16x8*)(Bl + gb);
        __syncthreads();
        *(u16x8*)&sAh[srow][skq] = va;
        *(u16x8*)&sAl[srow][skq] = vb;
        *(u16x8*)&sBh[srow][skq] = vc;
        *(u16x8*)&sBl[srow][skq] = vd;
        __syncthreads();
        s16x8 ah0 = *(const s16x8*)&sAh[wr * 32 + lc][lr * 8];
        s16x8 ah1 = *(const s16x8*)&sAh[wr * 32 + 16 + lc][lr * 8];
        s16x8 al0 = *(const s16x8*)&sAl[wr * 32 + lc][lr * 8];
        s16x8 al1 = *(const s16x8*)&sAl[wr * 32 + 16 + lc][lr * 8];
        s16x8 bh0 = *(const s16x8*)&sBh[wc * 32 + lc][lr * 8];
        s16x8 bh1 = *(const s16x8*)&sBh[wc * 32 + 16 + lc][lr * 8];
        s16x8 bl0 = *(const s16x8*)&sBl[wc * 32 + lc][lr * 8];
        s16x8 bl1 = *(const s16x8*)&sBl[wc * 32 + 16 + lc][lr * 8];
        acc[0][0] = mfma16(ah0, bh0, acc[0][0]);
        acc[0][0] = mfma16(ah0, bl0, acc[0][0]);
        acc[0][0] = mfma16(al0, bh0, acc[0][0]);
        acc[0][1] = mfma16(ah0, bh1, acc[0][1]);
        acc[0][1] = mfma16(ah0, bl1, acc[0][1]);
        acc[0][1] = mfma16(al0, bh1, acc[0][1]);
        acc[1][0] = mfma16(ah1, bh0, acc[1][0]);
        acc[1][0] = mfma16(ah1, bl0, acc[1][0]);
        acc[1][0] = mfma16(al1, bh0, acc[1][0]);
        acc[1][1] = mfma16(ah1, bh1, acc[1][1]);
        acc[1][1] = mfma16(ah1, bl1, acc[1][1]);
        acc[1][1] = mfma16(al1, bh1, acc[1][1]);
    }

#pragma unroll
    for (int fi = 0; fi < 2; ++fi)
#pragma unroll
        for (int fj = 0; fj < 2; ++fj) {
            f32x4 d = acc[fi][fj];
#pragma unroll
            for (int r = 0; r < 4; ++r) {
                int i = i0 + wr * 32 + fi * 16 + lr * 4 + r;
                int j = j0 + wc * 32 + fj * 16 + lc;
                size_t o = (size_t)i * N + j;
                float vv = d[r];
                if (EPI == 0) {
                    Cf[o] = vv;
                } else if (EPI == 1) {
                    Cf[o] = fmaxf(vv, 0.f);
                } else if (EPI == 2) {
                    vv = fmaxf(vv, 0.f);
                    float m = b2f(Mulh[o]) + b2f(Mull[o]);
                    vv *= m;
                    unsigned int pp = split2(vv);
                    Ch[o] = (U16)pp; Cl[o] = (U16)(pp >> 16);
                } else {
                    float w = 0.f;
                    if (j < i) w = exp2f((float)(i - 1 - j) * L2D) * vv;
                    unsigned int pp = split2(w);
                    Ch[o] = (U16)pp; Cl[o] = (U16)(pp >> 16);
                }
            }
        }
}

extern "C" void kernel_launch(void* const* d_in, const int* in_sizes, int n_in,
                              void* d_out, int out_size, void* d_ws, size_t ws_size,
                              hipStream_t stream) {
    (void)in_sizes; (void)n_in; (void)out_size; (void)ws_size;
    const float* emb = (const float*)d_in[0];   // (B,T,d)
    const float* E   = (const float*)d_in[1];   // (d,n)
    const float* Dx  = (const float*)d_in[2];   // (n,d)
    const float* Dy  = (const float*)d_in[3];   // (n,d)
    float* out = (float*)d_out;                 // (B,T,d)

    char* wsb = (char*)d_ws;
    // split-bf16 input copies
    U16* embh = (U16*)(wsb + 0);         // 1 MB   (a f32 overlays embh+embl later)
    U16* embl = (U16*)(wsb + 1048576);   // 1 MB
    U16* Eh   = (U16*)(wsb + 2097152);   // 512 KB
    U16* El   = (U16*)(wsb + 2621440);
    U16* Dxh  = (U16*)(wsb + 3145728);
    U16* Dxl  = (U16*)(wsb + 3670016);
    U16* Dyh  = (U16*)(wsb + 4194304);
    U16* Dyl  = (U16*)(wsb + 4718592);
    U16* lnvTh = (U16*)(wsb + 5242880);  // 1 MB  (v f32 overlays lnvT later)
    U16* lnvTl = (U16*)(wsb + 6291456);  // 1 MB
    float* xu  = (float*)(wsb + 7340032);   // 8 MB  (yh/yl overlay later)
    float* S   = (float*)(wsb + 15728640);  // 8 KB
    float* rc  = (float*)(wsb + 15736832);  // 8 KB
    U16* xh    = (U16*)(wsb + 15745024);    // 4 MB
    U16* xl    = (U16*)(wsb + 19939328);    // 4 MB
    U16* Wh    = (U16*)(wsb + 24133632);    // 1 MB  (alnh overlays after use)
    U16* Wl    = (U16*)(wsb + 25182208);    // 1 MB  (alnl overlays after use)
    // overlays (non-overlapping lifetimes)
    float* a    = (float*)(wsb + 0);         // 2 MB over emb splits (dead post-GEMM2)
    U16* alnh   = Wh;                        // over W (dead post-GEMM7)
    U16* alnl   = Wl;
    U16* yh     = (U16*)(wsb + 7340032);     // over xu (dead post-xscan)
    U16* yl     = (U16*)(wsb + 11534336);
    float* v    = (float*)(wsb + 5242880);   // 2 MB over lnvT (dead post-GEMM7)

    // 1. split-convert inputs
    cvt_kernel<<<1280, 256, 0, stream>>>(emb, E, Dx, Dy,
        embh, embl, Eh, El, Dxh, Dxl, Dyh, Dyl);
    // 2. lnvT = LN(emb) transposed split
    ln_kernel<2><<<ROWS / 4, 256, 0, stream>>>(emb, nullptr, lnvTh, lnvTl);
    // 3. xu = relu(emb @ Dx^T)   M=2048 N=1024 K=256
    mfma_nt_kernel<1><<<dim3(NN / 64, ROWS / 64, 1), 256, 0, stream>>>(
        embh, embl, Dxh, Dxl, xu, nullptr, nullptr, nullptr, nullptr, NN, DD, 0, 0, 0);
    // 4. S = rowsum(xu)
    rowsum_kernel<<<ROWS / 4, 256, 0, stream>>>(xu, S);
    // 5. normalizer scan
    cscan_kernel<<<1, 64, 0, stream>>>(S, rc);
    // 6. x scan -> split bf16
    xscan_kernel<<<BB * (NN / 16), 256, 0, stream>>>(xu, rc, xh, xl);
    // 7. W = mask . (X X^T)  batched  M=N=256 K=1024
    mfma_nt_kernel<3><<<dim3(TT / 64, TT / 64, BB), 256, 0, stream>>>(
        xh, xl, xh, xl, nullptr, Wh, Wl, nullptr, nullptr, TT, NN,
        (long long)TT * NN, (long long)TT * NN, (long long)TT * TT);
    // 8. a = W @ lnv  batched  M=256 N=256 K=256 (B = lnvT rows)
    mfma_nt_kernel<0><<<dim3(DD / 64, TT / 64, BB), 256, 0, stream>>>(
        Wh, Wl, lnvTh, lnvTl, a, nullptr, nullptr, nullptr, nullptr, DD, TT,
        (long long)TT * TT, (long long)DD * TT, (long long)TT * DD);
    // 9. aln = LN(a) split
    ln_kernel<1><<<ROWS / 4, 256, 0, stream>>>(a, nullptr, alnh, alnl);
    // 10. y = relu(aln @ Dy^T) * x -> split   M=2048 N=1024 K=256
    mfma_nt_kernel<2><<<dim3(NN / 64, ROWS / 64, 1), 256, 0, stream>>>(
        alnh, alnl, Dyh, Dyl, nullptr, yh, yl, xh, xl, NN, DD, 0, 0, 0);
    // 11. v = y @ E^T   M=2048 N=256 K=1024
    mfma_nt_kernel<0><<<dim3(DD / 64, ROWS / 64, 1), 256, 0, stream>>>(
        yh, yl, Eh, El, v, nullptr, nullptr, nullptr, nullptr, DD, NN, 0, 0, 0);
    // 12. out = LN(v)
    ln_kernel<0><<<ROWS / 4, 256, 0, stream>>>(v, out, nullptr, nullptr);
}

// Round 5
// 123.418 us; speedup vs baseline: 2.1291x; 1.0159x over previous
//
#include <hip/hip_runtime.h>
#include <math.h>

// BDH recurrence, parallelized + MFMA (split-bf16 hi/lo = f32-accuracy GEMMs):
//   xu = relu(emb @ Dx^T)                       MFMA GEMM 64x128 (f32 out)
//   S_t = rowsum ; c_t scalar scan ; x chunked affine scan (split-bf16 x out)
//   W[t,s] = (s<t) 0.97^(t-1-s) * (x_t . x_s)   MFMA GEMM 64x64 + mask (split out)
//   a = W @ lnvT^T                              MFMA GEMM 64x64 (f32 out)
//   y = relu(LN(a) @ Dy^T) * x                  MFMA GEMM 64x128 (split out)
//   out = LN(y @ E^T)                           MFMA GEMM 64x64 + LN

#define TT 256
#define BB 8
#define DD 256
#define NN 1024
#define ROWS (BB*TT)   // 2048

typedef unsigned short U16;
using s16x8 = __attribute__((ext_vector_type(8))) short;
using u16x8 = __attribute__((ext_vector_type(8))) unsigned short;
using u16x4 = __attribute__((ext_vector_type(4))) unsigned short;
using f32x4 = __attribute__((ext_vector_type(4))) float;

__device__ inline U16 bf16h(float f) {
    unsigned int u = __builtin_bit_cast(unsigned int, f);
    u += 0x7FFFu + ((u >> 16) & 1u);
    return (U16)(u >> 16);
}
__device__ inline float b2f(U16 h) {
    return __builtin_bit_cast(float, (unsigned int)h << 16);
}
// returns hi in bits [15:0], lo in bits [31:16]
__device__ inline unsigned int split2(float f) {
    U16 h = bf16h(f);
    U16 l = bf16h(f - b2f(h));
    return (unsigned int)h | ((unsigned int)l << 16);
}
__device__ inline f32x4 mfma16(s16x8 a, s16x8 b, f32x4 c) {
    return __builtin_amdgcn_mfma_f32_16x16x32_bf16(a, b, c, 0, 0, 0);
}

// ---------------- convert the 4 f32 inputs to split bf16 -------------------
__launch_bounds__(256)
__global__ void cvt_kernel(const float* __restrict__ e0, const float* __restrict__ e1,
                           const float* __restrict__ e2, const float* __restrict__ e3,
                           U16* h0, U16* l0, U16* h1, U16* l1,
                           U16* h2, U16* l2, U16* h3, U16* l3) {
    int base = (blockIdx.x * 256 + threadIdx.x) * 4;
    const float* s; U16 *dh, *dl; int loc;
    if      (base <  524288) { s = e0; dh = h0; dl = l0; loc = base; }
    else if (base <  786432) { s = e1; dh = h1; dl = l1; loc = base - 524288; }
    else if (base < 1048576) { s = e2; dh = h2; dl = l2; loc = base - 786432; }
    else                     { s = e3; dh = h3; dl = l3; loc = base - 1048576; }
    float4 v = *(const float4*)(s + loc);
    unsigned int p0 = split2(v.x), p1 = split2(v.y), p2 = split2(v.z), p3 = split2(v.w);
    u16x4 hh = {(U16)p0, (U16)p1, (U16)p2, (U16)p3};
    u16x4 ll = {(U16)(p0 >> 16), (U16)(p1 >> 16), (U16)(p2 >> 16), (U16)(p3 >> 16)};
    *(u16x4*)(dh + loc) = hh;
    *(u16x4*)(dl + loc) = ll;
}

// ---------------- LayerNorm rows of 256 ------------------------------------
// MODE 0: f32 rows out.  MODE 1: split-bf16 rows out.
template <int MODE>
__launch_bounds__(256)
__global__ void ln_kernel(const float* __restrict__ in, float* __restrict__ outf,
                          U16* __restrict__ outh, U16* __restrict__ outl) {
    int wave = threadIdx.x >> 6;
    int lane = threadIdx.x & 63;
    int row  = blockIdx.x * 4 + wave;
    const float* p = in + (size_t)row * DD;
    float4 v = *(const float4*)(p + lane * 4);
    float s  = v.x + v.y + v.z + v.w;
    float s2 = v.x*v.x + v.y*v.y + v.z*v.z + v.w*v.w;
#pragma unroll
    for (int o = 32; o; o >>= 1) {
        s  += __shfl_xor(s,  o, 64);
        s2 += __shfl_xor(s2, o, 64);
    }
    float m   = s * (1.0f / 256.0f);
    float var = s2 * (1.0f / 256.0f) - m * m;
    float sc  = rsqrtf(var + 1e-5f);
    float r4[4] = {(v.x - m) * sc, (v.y - m) * sc, (v.z - m) * sc, (v.w - m) * sc};
    if (MODE == 0) {
        float4 o4 = {r4[0], r4[1], r4[2], r4[3]};
        *(float4*)(outf + (size_t)row * DD + lane * 4) = o4;
    } else {
        u16x4 hh, ll;
#pragma unroll
        for (int u = 0; u < 4; ++u) {
            unsigned int pp = split2(r4[u]);
            hh[u] = (U16)pp; ll[u] = (U16)(pp >> 16);
        }
        *(u16x4*)(outh + (size_t)row * DD + lane * 4) = hh;
        *(u16x4*)(outl + (size_t)row * DD + lane * 4) = ll;
    }
}

// ---------------- LayerNorm + transpose: outT[b][j][t], coalesced ----------
// Block = 16 t-rows of one b; LDS transpose; each thread writes 2x16B runs.
__launch_bounds__(256)
__global__ void lnT_kernel(const float* __restrict__ in,
                           U16* __restrict__ outh, U16* __restrict__ outl) {
    __shared__ U16 lh[256][24], ll_[256][24];   // 24-u16 row = 48B: 16B-aligned
    const int b  = blockIdx.x >> 4;
    const int t0 = (blockIdx.x & 15) * 16;
    const int wave = threadIdx.x >> 6;
    const int lane = threadIdx.x & 63;
#pragma unroll
    for (int rr = 0; rr < 4; ++rr) {
        int tloc = wave * 4 + rr;
        const float* p = in + ((size_t)b * TT + t0 + tloc) * DD;
        float4 v = *(const float4*)(p + lane * 4);
        float s  = v.x + v.y + v.z + v.w;
        float s2 = v.x*v.x + v.y*v.y + v.z*v.z + v.w*v.w;
#pragma unroll
        for (int o = 32; o; o >>= 1) {
            s  += __shfl_xor(s,  o, 64);
            s2 += __shfl_xor(s2, o, 64);
        }
        float m   = s * (1.0f / 256.0f);
        float var = s2 * (1.0f / 256.0f) - m * m;
        float sc  = rsqrtf(var + 1e-5f);
        float r4[4] = {(v.x - m) * sc, (v.y - m) * sc, (v.z - m) * sc, (v.w - m) * sc};
#pragma unroll
        for (int u = 0; u < 4; ++u) {
            unsigned int pp = split2(r4[u]);
            int j = lane * 4 + u;
            lh[j][tloc]  = (U16)pp;
            ll_[j][tloc] = (U16)(pp >> 16);
        }
    }
    __syncthreads();
    int j = threadIdx.x;
    size_t o = ((size_t)b * DD + j) * TT + t0;
    u16x8 w0 = *(const u16x8*)&lh[j][0];
    u16x8 w1 = *(const u16x8*)&lh[j][8];
    *(u16x8*)(outh + o) = w0;
    *(u16x8*)(outh + o + 8) = w1;
    w0 = *(const u16x8*)&ll_[j][0];
    w1 = *(const u16x8*)&ll_[j][8];
    *(u16x8*)(outl + o) = w0;
    *(u16x8*)(outl + o + 8) = w1;
}

// ---------------- row sums of xu -------------------------------------------
__launch_bounds__(256)
__global__ void rowsum_kernel(const float* __restrict__ xu, float* __restrict__ S) {
    int wave = threadIdx.x >> 6;
    int lane = threadIdx.x & 63;
    int row  = blockIdx.x * 4 + wave;
    const float* p = xu + (size_t)row * NN;
    float s = 0.f;
#pragma unroll
    for (int w = 0; w < 4; ++w) {
        float4 v = *(const float4*)(p + w * 256 + lane * 4);
        s += v.x + v.y + v.z + v.w;
    }
#pragma unroll
    for (int o = 32; o; o >>= 1) s += __shfl_xor(s, o, 64);
    if (lane == 0) S[row] = s;
}

// ---------------- scalar normalizer scan -> reciprocals --------------------
__launch_bounds__(64)
__global__ void cscan_kernel(const float* __restrict__ S, float* __restrict__ rc) {
    int b = threadIdx.x;
    if (b >= BB) return;
    float sigma = 0.f;
    for (int t = 0; t < TT; ++t) {
        float us = 0.97f * sigma + S[b * TT + t];
        float cc = fmaxf(us, 1e-12f);
        float r  = 1.0f / cc;
        rc[b * TT + t] = r;
        sigma = us * r;
    }
}

// ---------------- chunked x scan; writes split-bf16 x ----------------------
__launch_bounds__(256)
__global__ void xscan_kernel(const float* __restrict__ xu, const float* __restrict__ rc,
                             U16* __restrict__ xh, U16* __restrict__ xl) {
    __shared__ float Gs[16][16], Hs[16][16], Cs[16][16];
    const int b    = blockIdx.x >> 6;
    const int jgrp = blockIdx.x & 63;
    const int tid  = threadIdx.x;
    const int ck   = tid >> 4;
    const int jl   = tid & 15;
    const int j    = jgrp * 16 + jl;
    const size_t base = ((size_t)b * TT + ck * 16) * NN + j;
    float xur[16], rcr[16];
#pragma unroll
    for (int i = 0; i < 16; ++i) xur[i] = xu[base + (size_t)i * NN];
#pragma unroll
    for (int i = 0; i < 16; ++i) rcr[i] = rc[b * TT + ck * 16 + i];
    float xs = 0.f, G = 1.f;
#pragma unroll
    for (int i = 0; i < 16; ++i) {
        xs = fmaf(0.97f, xs, xur[i]) * rcr[i];
        G *= 0.97f * rcr[i];
    }
    Gs[ck][jl] = G;
    Hs[ck][jl] = xs;
    __syncthreads();
    if (tid < 16) {
        float cr = 0.f;
        Cs[0][tid] = 0.f;
#pragma unroll
        for (int cc = 0; cc < 15; ++cc) {
            cr = fmaf(Gs[cc][tid], cr, Hs[cc][tid]);
            Cs[cc + 1][tid] = cr;
        }
    }
    __syncthreads();
    xs = Cs[ck][jl];
#pragma unroll
    for (int i = 0; i < 16; ++i) {
        xs = fmaf(0.97f, xs, xur[i]) * rcr[i];
        unsigned int pp = split2(xs);
        xh[base + (size_t)i * NN] = (U16)pp;
        xl[base + (size_t)i * NN] = (U16)(pp >> 16);
    }
}

// ---------------- split-bf16 MFMA NT GEMM, 64x64 tile ----------------------
// C[i,j] = sum_k A[i,k]*B[j,k].  4 waves, each 32x32 (2x2 16x16 frags), BK=32.
// EPI: 0 none->f32; 3 decay-mask->split.
template <int EPI>
__launch_bounds__(256)
__global__ void mfma_nt_kernel(const U16* __restrict__ Ah, const U16* __restrict__ Al,
                               const U16* __restrict__ Bh, const U16* __restrict__ Bl,
                               float* __restrict__ Cf, U16* __restrict__ Ch, U16* __restrict__ Cl,
                               int N, int K,
                               long long sA, long long sB, long long sC) {
    const int z = blockIdx.z;
    Ah += (size_t)z * sA; Al += (size_t)z * sA;
    Bh += (size_t)z * sB; Bl += (size_t)z * sB;
    if (EPI == 0) { Cf += (size_t)z * sC; }
    else          { Ch += (size_t)z * sC; Cl += (size_t)z * sC; }
    const int i0 = blockIdx.y * 64, j0 = blockIdx.x * 64;
    const int t = threadIdx.x, lane = t & 63, wid = t >> 6;
    const int wr = wid >> 1, wc = wid & 1;
    const int lr = lane >> 4, lc = lane & 15;
    const float L2D = -0.043943348f;  // log2(0.97)

    if (EPI == 3 && j0 > i0) {        // fully-masked tile: zero-fill
#pragma unroll
        for (int fi = 0; fi < 2; ++fi)
#pragma unroll
            for (int fj = 0; fj < 2; ++fj)
#pragma unroll
                for (int r = 0; r < 4; ++r) {
                    int i = i0 + wr * 32 + fi * 16 + lr * 4 + r;
                    int j = j0 + wc * 32 + fj * 16 + lc;
                    size_t o = (size_t)i * N + j;
                    Ch[o] = 0; Cl[o] = 0;
                }
        return;
    }

    __shared__ __align__(16) U16 sAh[64][40], sAl[64][40], sBh[64][40], sBl[64][40];
    const int srow = t >> 2, skq = (t & 3) * 8;
    f32x4 acc[2][2];
    const f32x4 z4 = {0.f, 0.f, 0.f, 0.f};
    acc[0][0] = z4; acc[0][1] = z4; acc[1][0] = z4; acc[1][1] = z4;

    for (int k0 = 0; k0 < K; k0 += 32) {
        const size_t ga = (size_t)(i0 + srow) * K + k0 + skq;
        const size_t gb = (size_t)(j0 + srow) * K + k0 + skq;
        u16x8 va = *(const u16x8*)(Ah + ga);
        u16x8 vb = *(const u16x8*)(Al + ga);
        u16x8 vc = *(const u16x8*)(Bh + gb);
        u16x8 vd = *(const u16x8*)(Bl + gb);
        __syncthreads();
        *(u16x8*)&sAh[srow][skq] = va;
        *(u16x8*)&sAl[srow][skq] = vb;
        *(u16x8*)&sBh[srow][skq] = vc;
        *(u16x8*)&sBl[srow][skq] = vd;
        __syncthreads();
        s16x8 ah0 = *(const s16x8*)&sAh[wr * 32 + lc][lr * 8];
        s16x8 ah1 = *(const s16x8*)&sAh[wr * 32 + 16 + lc][lr * 8];
        s16x8 al0 = *(const s16x8*)&sAl[wr * 32 + lc][lr * 8];
        s16x8 al1 = *(const s16x8*)&sAl[wr * 32 + 16 + lc][lr * 8];
        s16x8 bh0 = *(const s16x8*)&sBh[wc * 32 + lc][lr * 8];
        s16x8 bh1 = *(const s16x8*)&sBh[wc * 32 + 16 + lc][lr * 8];
        s16x8 bl0 = *(const s16x8*)&sBl[wc * 32 + lc][lr * 8];
        s16x8 bl1 = *(const s16x8*)&sBl[wc * 32 + 16 + lc][lr * 8];
        acc[0][0] = mfma16(ah0, bh0, acc[0][0]);
        acc[0][0] = mfma16(ah0, bl0, acc[0][0]);
        acc[0][0] = mfma16(al0, bh0, acc[0][0]);
        acc[0][1] = mfma16(ah0, bh1, acc[0][1]);
        acc[0][1] = mfma16(ah0, bl1, acc[0][1]);
        acc[0][1] = mfma16(al0, bh1, acc[0][1]);
        acc[1][0] = mfma16(ah1, bh0, acc[1][0]);
        acc[1][0] = mfma16(ah1, bl0, acc[1][0]);
        acc[1][0] = mfma16(al1, bh0, acc[1][0]);
        acc[1][1] = mfma16(ah1, bh1, acc[1][1]);
        acc[1][1] = mfma16(ah1, bl1, acc[1][1]);
        acc[1][1] = mfma16(al1, bh1, acc[1][1]);
    }

#pragma unroll
    for (int fi = 0; fi < 2; ++fi)
#pragma unroll
        for (int fj = 0; fj < 2; ++fj) {
            f32x4 d = acc[fi][fj];
#pragma unroll
            for (int r = 0; r < 4; ++r) {
                int i = i0 + wr * 32 + fi * 16 + lr * 4 + r;
                int j = j0 + wc * 32 + fj * 16 + lc;
                size_t o = (size_t)i * N + j;
                float vv = d[r];
                if (EPI == 0) {
                    Cf[o] = vv;
                } else {
                    float w = 0.f;
                    if (j < i) w = exp2f((float)(i - 1 - j) * L2D) * vv;
                    unsigned int pp = split2(w);
                    Ch[o] = (U16)pp; Cl[o] = (U16)(pp >> 16);
                }
            }
        }
}

// ---------------- split-bf16 MFMA NT GEMM, 64x128 tile ---------------------
// 4 waves, each 32x64 (2x4 16x16 frags), BK=32.  Better ds_read:MFMA ratio.
// EPI: 1 relu->f32; 2 relu*(Mulh+Mull)->split.
template <int EPI>
__launch_bounds__(256)
__global__ void mfma_nt128_kernel(const U16* __restrict__ Ah, const U16* __restrict__ Al,
                                  const U16* __restrict__ Bh, const U16* __restrict__ Bl,
                                  float* __restrict__ Cf, U16* __restrict__ Ch, U16* __restrict__ Cl,
                                  const U16* __restrict__ Mulh, const U16* __restrict__ Mull,
                                  int N, int K) {
    const int i0 = blockIdx.y * 64, j0 = blockIdx.x * 128;
    const int t = threadIdx.x, lane = t & 63, wid = t >> 6;
    const int wr = wid >> 1, wc = wid & 1;
    const int lr = lane >> 4, lc = lane & 15;

    __shared__ __align__(16) U16 sAh[64][40], sAl[64][40], sBh[128][40], sBl[128][40];
    const int arow = t >> 2, akq = (t & 3) * 8;
    const int brow0 = t >> 1;               // unused; kept simple below
    (void)brow0;
    f32x4 acc[2][4];
    const f32x4 z4 = {0.f, 0.f, 0.f, 0.f};
#pragma unroll
    for (int fi = 0; fi < 2; ++fi)
#pragma unroll
        for (int fj = 0; fj < 4; ++fj) acc[fi][fj] = z4;

    for (int k0 = 0; k0 < K; k0 += 32) {
        const size_t ga = (size_t)(i0 + arow) * K + k0 + akq;
        u16x8 va = *(const u16x8*)(Ah + ga);
        u16x8 vb = *(const u16x8*)(Al + ga);
        // B: 128 rows x 4 chunks = 512 chunks; 2 per thread
        const int c0 = t, c1 = t + 256;
        const int b0r = c0 >> 2, b0q = (c0 & 3) * 8;
        const int b1r = c1 >> 2, b1q = (c1 & 3) * 8;
        const size_t gb0 = (size_t)(j0 + b0r) * K + k0 + b0q;
        const size_t gb1 = (size_t)(j0 + b1r) * K + k0 + b1q;
        u16x8 vc0 = *(const u16x8*)(Bh + gb0);
        u16x8 vc1 = *(const u16x8*)(Bh + gb1);
        u16x8 vd0 = *(const u16x8*)(Bl + gb0);
        u16x8 vd1 = *(const u16x8*)(Bl + gb1);
        __syncthreads();
        *(u16x8*)&sAh[arow][akq] = va;
        *(u16x8*)&sAl[arow][akq] = vb;
        *(u16x8*)&sBh[b0r][b0q] = vc0;
        *(u16x8*)&sBh[b1r][b1q] = vc1;
        *(u16x8*)&sBl[b0r][b0q] = vd0;
        *(u16x8*)&sBl[b1r][b1q] = vd1;
        __syncthreads();
        s16x8 ah[2], al[2], bh[4], bl[4];
#pragma unroll
        for (int fi = 0; fi < 2; ++fi) {
            ah[fi] = *(const s16x8*)&sAh[wr * 32 + fi * 16 + lc][lr * 8];
            al[fi] = *(const s16x8*)&sAl[wr * 32 + fi * 16 + lc][lr * 8];
        }
#pragma unroll
        for (int fj = 0; fj < 4; ++fj) {
            bh[fj] = *(const s16x8*)&sBh[wc * 64 + fj * 16 + lc][lr * 8];
            bl[fj] = *(const s16x8*)&sBl[wc * 64 + fj * 16 + lc][lr * 8];
        }
#pragma unroll
        for (int fi = 0; fi < 2; ++fi)
#pragma unroll
            for (int fj = 0; fj < 4; ++fj) {
                acc[fi][fj] = mfma16(ah[fi], bh[fj], acc[fi][fj]);
                acc[fi][fj] = mfma16(ah[fi], bl[fj], acc[fi][fj]);
                acc[fi][fj] = mfma16(al[fi], bh[fj], acc[fi][fj]);
            }
    }

#pragma unroll
    for (int fi = 0; fi < 2; ++fi)
#pragma unroll
        for (int fj = 0; fj < 4; ++fj) {
            f32x4 d = acc[fi][fj];
#pragma unroll
            for (int r = 0; r < 4; ++r) {
                int i = i0 + wr * 32 + fi * 16 + lr * 4 + r;
                int j = j0 + wc * 64 + fj * 16 + lc;
                size_t o = (size_t)i * N + j;
                float vv = fmaxf(d[r], 0.f);
                if (EPI == 1) {
                    Cf[o] = vv;
                } else {
                    float m = b2f(Mulh[o]) + b2f(Mull[o]);
                    vv *= m;
                    unsigned int pp = split2(vv);
                    Ch[o] = (U16)pp; Cl[o] = (U16)(pp >> 16);
                }
            }
        }
}

extern "C" void kernel_launch(void* const* d_in, const int* in_sizes, int n_in,
                              void* d_out, int out_size, void* d_ws, size_t ws_size,
                              hipStream_t stream) {
    (void)in_sizes; (void)n_in; (void)out_size; (void)ws_size;
    const float* emb = (const float*)d_in[0];   // (B,T,d)
    const float* E   = (const float*)d_in[1];   // (d,n)
    const float* Dx  = (const float*)d_in[2];   // (n,d)
    const float* Dy  = (const float*)d_in[3];   // (n,d)
    float* out = (float*)d_out;                 // (B,T,d)

    char* wsb = (char*)d_ws;
    // split-bf16 input copies
    U16* embh = (U16*)(wsb + 0);         // 1 MB   (a f32 overlays embh+embl later)
    U16* embl = (U16*)(wsb + 1048576);   // 1 MB
    U16* Eh   = (U16*)(wsb + 2097152);   // 512 KB
    U16* El   = (U16*)(wsb + 2621440);
    U16* Dxh  = (U16*)(wsb + 3145728);
    U16* Dxl  = (U16*)(wsb + 3670016);
    U16* Dyh  = (U16*)(wsb + 4194304);
    U16* Dyl  = (U16*)(wsb + 4718592);
    U16* lnvTh = (U16*)(wsb + 5242880);  // 1 MB  (v f32 overlays lnvT later)
    U16* lnvTl = (U16*)(wsb + 6291456);  // 1 MB
    float* xu  = (float*)(wsb + 7340032);   // 8 MB  (yh/yl overlay later)
    float* S   = (float*)(wsb + 15728640);  // 8 KB
    float* rc  = (float*)(wsb + 15736832);  // 8 KB
    U16* xh    = (U16*)(wsb + 15745024);    // 4 MB
    U16* xl    = (U16*)(wsb + 19939328);    // 4 MB
    U16* Wh    = (U16*)(wsb + 24133632);    // 1 MB  (alnh overlays after use)
    U16* Wl    = (U16*)(wsb + 25182208);    // 1 MB  (alnl overlays after use)
    // overlays (non-overlapping lifetimes)
    float* a    = (float*)(wsb + 0);         // 2 MB over emb splits (dead post-GEMM a)
    U16* alnh   = Wh;                        // over W (dead post-GEMM a)
    U16* alnl   = Wl;
    U16* yh     = (U16*)(wsb + 7340032);     // over xu (dead post-xscan)
    U16* yl     = (U16*)(wsb + 11534336);
    float* v    = (float*)(wsb + 5242880);   // 2 MB over lnvT (dead post-GEMM a)

    // 1. split-convert inputs
    cvt_kernel<<<1280, 256, 0, stream>>>(emb, E, Dx, Dy,
        embh, embl, Eh, El, Dxh, Dxl, Dyh, Dyl);
    // 2. lnvT = LN(emb) transposed split (LDS transpose, coalesced)
    lnT_kernel<<<ROWS / 16, 256, 0, stream>>>(emb, lnvTh, lnvTl);
    // 3. xu = relu(emb @ Dx^T)   M=2048 N=1024 K=256   (64x128 tiles)
    mfma_nt128_kernel<1><<<dim3(NN / 128, ROWS / 64), 256, 0, stream>>>(
        embh, embl, Dxh, Dxl, xu, nullptr, nullptr, nullptr, nullptr, NN, DD);
    // 4. S = rowsum(xu)
    rowsum_kernel<<<ROWS / 4, 256, 0, stream>>>(xu, S);
    // 5. normalizer scan
    cscan_kernel<<<1, 64, 0, stream>>>(S, rc);
    // 6. x scan -> split bf16
    xscan_kernel<<<BB * (NN / 16), 256, 0, stream>>>(xu, rc, xh, xl);
    // 7. W = mask . (X X^T)  batched  M=N=256 K=1024
    mfma_nt_kernel<3><<<dim3(TT / 64, TT / 64, BB), 256, 0, stream>>>(
        xh, xl, xh, xl, nullptr, Wh, Wl, TT, NN,
        (long long)TT * NN, (long long)TT * NN, (long long)TT * TT);
    // 8. a = W @ lnv  batched  M=256 N=256 K=256 (B = lnvT rows)
    mfma_nt_kernel<0><<<dim3(DD / 64, TT / 64, BB), 256, 0, stream>>>(
        Wh, Wl, lnvTh, lnvTl, a, nullptr, nullptr, DD, TT,
        (long long)TT * TT, (long long)DD * TT, (long long)TT * DD);
    // 9. aln = LN(a) split
    ln_kernel<1><<<ROWS / 4, 256, 0, stream>>>(a, nullptr, alnh, alnl);
    // 10. y = relu(aln @ Dy^T) * x -> split   M=2048 N=1024 K=256  (64x128)
    mfma_nt128_kernel<2><<<dim3(NN / 128, ROWS / 64), 256, 0, stream>>>(
        alnh, alnl, Dyh, Dyl, nullptr, yh, yl, xh, xl, NN, DD);
    // 11. v = y @ E^T   M=2048 N=256 K=1024
    mfma_nt_kernel<0><<<dim3(DD / 64, ROWS / 64, 1), 256, 0, stream>>>(
        yh, yl, Eh, El, v, nullptr, nullptr, DD, NN, 0, 0, 0);
    // 12. out = LN(v)
    ln_kernel<0><<<ROWS / 4, 256, 0, stream>>>(v, out, nullptr, nullptr);
}

// Round 6
// 112.835 us; speedup vs baseline: 2.3288x; 1.0938x over previous
//
#include <hip/hip_runtime.h>
#include <math.h>

// BDH recurrence, parallelized + MFMA (split-bf16 hi/lo = f32-accuracy GEMMs):
//   xu = relu(emb @ Dx^T)                       MFMA GEMM 64x128 (f32 out)
//   S_t = rowsum ; c_t scalar scan (LDS) ; x chunked affine scan
//   W[t,s] = (s<t) 0.97^(t-1-s) * (x_t . x_s)   MFMA GEMM 64x64 + mask (split out)
//   a = W @ lnvT^T                              MFMA GEMM 64x64 (f32 out)
//   y = relu(LN(a) @ Dy^T) * x                  MFMA GEMM 64x128 (split out)
//   out = LN(y @ E^T)                           MFMA GEMM 64x64 + LN

#define TT 256
#define BB 8
#define DD 256
#define NN 1024
#define ROWS (BB*TT)   // 2048

typedef unsigned short U16;
using s16x8 = __attribute__((ext_vector_type(8))) short;
using u16x8 = __attribute__((ext_vector_type(8))) unsigned short;
using u16x4 = __attribute__((ext_vector_type(4))) unsigned short;
using f32x4 = __attribute__((ext_vector_type(4))) float;

__device__ inline U16 bf16h(float f) {
    unsigned int u = __builtin_bit_cast(unsigned int, f);
    u += 0x7FFFu + ((u >> 16) & 1u);
    return (U16)(u >> 16);
}
__device__ inline float b2f(U16 h) {
    return __builtin_bit_cast(float, (unsigned int)h << 16);
}
// returns hi in bits [15:0], lo in bits [31:16]
__device__ inline unsigned int split2(float f) {
    U16 h = bf16h(f);
    U16 l = bf16h(f - b2f(h));
    return (unsigned int)h | ((unsigned int)l << 16);
}
__device__ inline f32x4 mfma16(s16x8 a, s16x8 b, f32x4 c) {
    return __builtin_amdgcn_mfma_f32_16x16x32_bf16(a, b, c, 0, 0, 0);
}

// ---------------- convert the 4 f32 inputs to split bf16 -------------------
__launch_bounds__(256)
__global__ void cvt_kernel(const float* __restrict__ e0, const float* __restrict__ e1,
                           const float* __restrict__ e2, const float* __restrict__ e3,
                           U16* h0, U16* l0, U16* h1, U16* l1,
                           U16* h2, U16* l2, U16* h3, U16* l3) {
    int base = (blockIdx.x * 256 + threadIdx.x) * 4;
    const float* s; U16 *dh, *dl; int loc;
    if      (base <  524288) { s = e0; dh = h0; dl = l0; loc = base; }
    else if (base <  786432) { s = e1; dh = h1; dl = l1; loc = base - 524288; }
    else if (base < 1048576) { s = e2; dh = h2; dl = l2; loc = base - 786432; }
    else                     { s = e3; dh = h3; dl = l3; loc = base - 1048576; }
    float4 v = *(const float4*)(s + loc);
    unsigned int p0 = split2(v.x), p1 = split2(v.y), p2 = split2(v.z), p3 = split2(v.w);
    u16x4 hh = {(U16)p0, (U16)p1, (U16)p2, (U16)p3};
    u16x4 ll = {(U16)(p0 >> 16), (U16)(p1 >> 16), (U16)(p2 >> 16), (U16)(p3 >> 16)};
    *(u16x4*)(dh + loc) = hh;
    *(u16x4*)(dl + loc) = ll;
}

// ---------------- LayerNorm rows of 256 ------------------------------------
// MODE 0: f32 rows out.  MODE 1: split-bf16 rows out.
template <int MODE>
__launch_bounds__(256)
__global__ void ln_kernel(const float* __restrict__ in, float* __restrict__ outf,
                          U16* __restrict__ outh, U16* __restrict__ outl) {
    int wave = threadIdx.x >> 6;
    int lane = threadIdx.x & 63;
    int row  = blockIdx.x * 4 + wave;
    const float* p = in + (size_t)row * DD;
    float4 v = *(const float4*)(p + lane * 4);
    float s  = v.x + v.y + v.z + v.w;
    float s2 = v.x*v.x + v.y*v.y + v.z*v.z + v.w*v.w;
#pragma unroll
    for (int o = 32; o; o >>= 1) {
        s  += __shfl_xor(s,  o, 64);
        s2 += __shfl_xor(s2, o, 64);
    }
    float m   = s * (1.0f / 256.0f);
    float var = s2 * (1.0f / 256.0f) - m * m;
    float sc  = rsqrtf(var + 1e-5f);
    float r4[4] = {(v.x - m) * sc, (v.y - m) * sc, (v.z - m) * sc, (v.w - m) * sc};
    if (MODE == 0) {
        float4 o4 = {r4[0], r4[1], r4[2], r4[3]};
        *(float4*)(outf + (size_t)row * DD + lane * 4) = o4;
    } else {
        u16x4 hh, ll;
#pragma unroll
        for (int u = 0; u < 4; ++u) {
            unsigned int pp = split2(r4[u]);
            hh[u] = (U16)pp; ll[u] = (U16)(pp >> 16);
        }
        *(u16x4*)(outh + (size_t)row * DD + lane * 4) = hh;
        *(u16x4*)(outl + (size_t)row * DD + lane * 4) = ll;
    }
}

// ---------------- LayerNorm + transpose: outT[b][j][t], coalesced ----------
// Block = 16 t-rows of one b; LDS transpose; each thread writes 2x16B runs.
__launch_bounds__(256)
__global__ void lnT_kernel(const float* __restrict__ in,
                           U16* __restrict__ outh, U16* __restrict__ outl) {
    __shared__ U16 lh[256][24], ll_[256][24];   // 24-u16 row = 48B: 16B-aligned
    const int b  = blockIdx.x >> 4;
    const int t0 = (blockIdx.x & 15) * 16;
    const int wave = threadIdx.x >> 6;
    const int lane = threadIdx.x & 63;
#pragma unroll
    for (int rr = 0; rr < 4; ++rr) {
        int tloc = wave * 4 + rr;
        const float* p = in + ((size_t)b * TT + t0 + tloc) * DD;
        float4 v = *(const float4*)(p + lane * 4);
        float s  = v.x + v.y + v.z + v.w;
        float s2 = v.x*v.x + v.y*v.y + v.z*v.z + v.w*v.w;
#pragma unroll
        for (int o = 32; o; o >>= 1) {
            s  += __shfl_xor(s,  o, 64);
            s2 += __shfl_xor(s2, o, 64);
        }
        float m   = s * (1.0f / 256.0f);
        float var = s2 * (1.0f / 256.0f) - m * m;
        float sc  = rsqrtf(var + 1e-5f);
        float r4[4] = {(v.x - m) * sc, (v.y - m) * sc, (v.z - m) * sc, (v.w - m) * sc};
#pragma unroll
        for (int u = 0; u < 4; ++u) {
            unsigned int pp = split2(r4[u]);
            int j = lane * 4 + u;
            lh[j][tloc]  = (U16)pp;
            ll_[j][tloc] = (U16)(pp >> 16);
        }
    }
    __syncthreads();
    int j = threadIdx.x;
    size_t o = ((size_t)b * DD + j) * TT + t0;
    u16x8 w0 = *(const u16x8*)&lh[j][0];
    u16x8 w1 = *(const u16x8*)&lh[j][8];
    *(u16x8*)(outh + o) = w0;
    *(u16x8*)(outh + o + 8) = w1;
    w0 = *(const u16x8*)&ll_[j][0];
    w1 = *(const u16x8*)&ll_[j][8];
    *(u16x8*)(outl + o) = w0;
    *(u16x8*)(outl + o + 8) = w1;
}

// ---------------- row sums of xu -------------------------------------------
__launch_bounds__(256)
__global__ void rowsum_kernel(const float* __restrict__ xu, float* __restrict__ S) {
    int wave = threadIdx.x >> 6;
    int lane = threadIdx.x & 63;
    int row  = blockIdx.x * 4 + wave;
    const float* p = xu + (size_t)row * NN;
    float s = 0.f;
#pragma unroll
    for (int w = 0; w < 4; ++w) {
        float4 v = *(const float4*)(p + w * 256 + lane * 4);
        s += v.x + v.y + v.z + v.w;
    }
#pragma unroll
    for (int o = 32; o; o >>= 1) s += __shfl_xor(s, o, 64);
    if (lane == 0) S[row] = s;
}

// ---------------- normalizer scan, LDS-resident -----------------------------
// One block. Phase 1: S -> LDS (padded, conflict-free). Phase 2: 8 serial
// scans with divide-free carry chain (sigma = us>=eps ? 1 : us*1e12f, exact
// per-branch match to us/max(us,eps) up to 1 ulp). Phase 3: rc = 1/max(us,eps)
// data-parallel across 256 threads.
__launch_bounds__(256)
__global__ void cscan_kernel(const float* __restrict__ S, float* __restrict__ rc) {
    __shared__ float sS[BB][TT + 1];
    __shared__ float sUS[BB][TT + 1];
    const int tid = threadIdx.x;
#pragma unroll
    for (int i = 0; i < ROWS / 256; ++i) {
        int idx = tid + i * 256;
        sS[idx >> 8][idx & 255] = S[idx];
    }
    __syncthreads();
    if (tid < BB) {
        float sigma = 0.f;
        for (int t = 0; t < TT; ++t) {
            float us = fmaf(0.97f, sigma, sS[tid][t]);
            sUS[tid][t] = us;
            sigma = (us >= 1e-12f) ? 1.0f : us * 1e12f;
        }
    }
    __syncthreads();
#pragma unroll
    for (int i = 0; i < ROWS / 256; ++i) {
        int idx = tid + i * 256;
        rc[idx] = 1.0f / fmaxf(sUS[idx >> 8][idx & 255], 1e-12f);
    }
}

// ---------------- chunked x scan; writes split-bf16 x ----------------------
__launch_bounds__(256)
__global__ void xscan_kernel(const float* __restrict__ xu, const float* __restrict__ rc,
                             U16* __restrict__ xh, U16* __restrict__ xl) {
    __shared__ float Gs[16][16], Hs[16][16], Cs[16][16];
    const int b    = blockIdx.x >> 6;
    const int jgrp = blockIdx.x & 63;
    const int tid  = threadIdx.x;
    const int ck   = tid >> 4;
    const int jl   = tid & 15;
    const int j    = jgrp * 16 + jl;
    const size_t base = ((size_t)b * TT + ck * 16) * NN + j;
    float xur[16], rcr[16];
#pragma unroll
    for (int i = 0; i < 16; ++i) xur[i] = xu[base + (size_t)i * NN];
#pragma unroll
    for (int i = 0; i < 16; ++i) rcr[i] = rc[b * TT + ck * 16 + i];
    float xs = 0.f, G = 1.f;
#pragma unroll
    for (int i = 0; i < 16; ++i) {
        xs = fmaf(0.97f, xs, xur[i]) * rcr[i];
        G *= 0.97f * rcr[i];
    }
    Gs[ck][jl] = G;
    Hs[ck][jl] = xs;
    __syncthreads();
    if (tid < 16) {
        float cr = 0.f;
        Cs[0][tid] = 0.f;
#pragma unroll
        for (int cc = 0; cc < 15; ++cc) {
            cr = fmaf(Gs[cc][tid], cr, Hs[cc][tid]);
            Cs[cc + 1][tid] = cr;
        }
    }
    __syncthreads();
    xs = Cs[ck][jl];
#pragma unroll
    for (int i = 0; i < 16; ++i) {
        xs = fmaf(0.97f, xs, xur[i]) * rcr[i];
        unsigned int pp = split2(xs);
        xh[base + (size_t)i * NN] = (U16)pp;
        xl[base + (size_t)i * NN] = (U16)(pp >> 16);
    }
}

// ---------------- split-bf16 MFMA NT GEMM, 64x64 tile ----------------------
// C[i,j] = sum_k A[i,k]*B[j,k].  4 waves, each 32x32 (2x2 16x16 frags), BK=32.
// EPI: 0 none->f32; 3 decay-mask->split.
template <int EPI>
__launch_bounds__(256)
__global__ void mfma_nt_kernel(const U16* __restrict__ Ah, const U16* __restrict__ Al,
                               const U16* __restrict__ Bh, const U16* __restrict__ Bl,
                               float* __restrict__ Cf, U16* __restrict__ Ch, U16* __restrict__ Cl,
                               int N, int K,
                               long long sA, long long sB, long long sC) {
    const int z = blockIdx.z;
    Ah += (size_t)z * sA; Al += (size_t)z * sA;
    Bh += (size_t)z * sB; Bl += (size_t)z * sB;
    if (EPI == 0) { Cf += (size_t)z * sC; }
    else          { Ch += (size_t)z * sC; Cl += (size_t)z * sC; }
    const int i0 = blockIdx.y * 64, j0 = blockIdx.x * 64;
    const int t = threadIdx.x, lane = t & 63, wid = t >> 6;
    const int wr = wid >> 1, wc = wid & 1;
    const int lr = lane >> 4, lc = lane & 15;
    const float L2D = -0.043943348f;  // log2(0.97)

    if (EPI == 3 && j0 > i0) {        // fully-masked tile: zero-fill
#pragma unroll
        for (int fi = 0; fi < 2; ++fi)
#pragma unroll
            for (int fj = 0; fj < 2; ++fj)
#pragma unroll
                for (int r = 0; r < 4; ++r) {
                    int i = i0 + wr * 32 + fi * 16 + lr * 4 + r;
                    int j = j0 + wc * 32 + fj * 16 + lc;
                    size_t o = (size_t)i * N + j;
                    Ch[o] = 0; Cl[o] = 0;
                }
        return;
    }

    __shared__ __align__(16) U16 sAh[64][40], sAl[64][40], sBh[64][40], sBl[64][40];
    const int srow = t >> 2, skq = (t & 3) * 8;
    f32x4 acc[2][2];
    const f32x4 z4 = {0.f, 0.f, 0.f, 0.f};
    acc[0][0] = z4; acc[0][1] = z4; acc[1][0] = z4; acc[1][1] = z4;

    for (int k0 = 0; k0 < K; k0 += 32) {
        const size_t ga = (size_t)(i0 + srow) * K + k0 + skq;
        const size_t gb = (size_t)(j0 + srow) * K + k0 + skq;
        u16x8 va = *(const u16x8*)(Ah + ga);
        u16x8 vb = *(const u16x8*)(Al + ga);
        u16x8 vc = *(const u16x8*)(Bh + gb);
        u16x8 vd = *(const u16x8*)(Bl + gb);
        __syncthreads();
        *(u16x8*)&sAh[srow][skq] = va;
        *(u16x8*)&sAl[srow][skq] = vb;
        *(u16x8*)&sBh[srow][skq] = vc;
        *(u16x8*)&sBl[srow][skq] = vd;
        __syncthreads();
        s16x8 ah0 = *(const s16x8*)&sAh[wr * 32 + lc][lr * 8];
        s16x8 ah1 = *(const s16x8*)&sAh[wr * 32 + 16 + lc][lr * 8];
        s16x8 al0 = *(const s16x8*)&sAl[wr * 32 + lc][lr * 8];
        s16x8 al1 = *(const s16x8*)&sAl[wr * 32 + 16 + lc][lr * 8];
        s16x8 bh0 = *(const s16x8*)&sBh[wc * 32 + lc][lr * 8];
        s16x8 bh1 = *(const s16x8*)&sBh[wc * 32 + 16 + lc][lr * 8];
        s16x8 bl0 = *(const s16x8*)&sBl[wc * 32 + lc][lr * 8];
        s16x8 bl1 = *(const s16x8*)&sBl[wc * 32 + 16 + lc][lr * 8];
        acc[0][0] = mfma16(ah0, bh0, acc[0][0]);
        acc[0][0] = mfma16(ah0, bl0, acc[0][0]);
        acc[0][0] = mfma16(al0, bh0, acc[0][0]);
        acc[0][1] = mfma16(ah0, bh1, acc[0][1]);
        acc[0][1] = mfma16(ah0, bl1, acc[0][1]);
        acc[0][1] = mfma16(al0, bh1, acc[0][1]);
        acc[1][0] = mfma16(ah1, bh0, acc[1][0]);
        acc[1][0] = mfma16(ah1, bl0, acc[1][0]);
        acc[1][0] = mfma16(al1, bh0, acc[1][0]);
        acc[1][1] = mfma16(ah1, bh1, acc[1][1]);
        acc[1][1] = mfma16(ah1, bl1, acc[1][1]);
        acc[1][1] = mfma16(al1, bh1, acc[1][1]);
    }

#pragma unroll
    for (int fi = 0; fi < 2; ++fi)
#pragma unroll
        for (int fj = 0; fj < 2; ++fj) {
            f32x4 d = acc[fi][fj];
#pragma unroll
            for (int r = 0; r < 4; ++r) {
                int i = i0 + wr * 32 + fi * 16 + lr * 4 + r;
                int j = j0 + wc * 32 + fj * 16 + lc;
                size_t o = (size_t)i * N + j;
                float vv = d[r];
                if (EPI == 0) {
                    Cf[o] = vv;
                } else {
                    float w = 0.f;
                    if (j < i) w = exp2f((float)(i - 1 - j) * L2D) * vv;
                    unsigned int pp = split2(w);
                    Ch[o] = (U16)pp; Cl[o] = (U16)(pp >> 16);
                }
            }
        }
}

// ---------------- split-bf16 MFMA NT GEMM, 64x128 tile ---------------------
// 4 waves, each 32x64 (2x4 16x16 frags), BK=32.  Better ds_read:MFMA ratio.
// EPI: 1 relu->f32; 2 relu*(Mulh+Mull)->split.
template <int EPI>
__launch_bounds__(256)
__global__ void mfma_nt128_kernel(const U16* __restrict__ Ah, const U16* __restrict__ Al,
                                  const U16* __restrict__ Bh, const U16* __restrict__ Bl,
                                  float* __restrict__ Cf, U16* __restrict__ Ch, U16* __restrict__ Cl,
                                  const U16* __restrict__ Mulh, const U16* __restrict__ Mull,
                                  int N, int K) {
    const int i0 = blockIdx.y * 64, j0 = blockIdx.x * 128;
    const int t = threadIdx.x, lane = t & 63, wid = t >> 6;
    const int wr = wid >> 1, wc = wid & 1;
    const int lr = lane >> 4, lc = lane & 15;

    __shared__ __align__(16) U16 sAh[64][40], sAl[64][40], sBh[128][40], sBl[128][40];
    const int arow = t >> 2, akq = (t & 3) * 8;
    f32x4 acc[2][4];
    const f32x4 z4 = {0.f, 0.f, 0.f, 0.f};
#pragma unroll
    for (int fi = 0; fi < 2; ++fi)
#pragma unroll
        for (int fj = 0; fj < 4; ++fj) acc[fi][fj] = z4;

    for (int k0 = 0; k0 < K; k0 += 32) {
        const size_t ga = (size_t)(i0 + arow) * K + k0 + akq;
        u16x8 va = *(const u16x8*)(Ah + ga);
        u16x8 vb = *(const u16x8*)(Al + ga);
        // B: 128 rows x 4 chunks = 512 chunks; 2 per thread
        const int c0 = t, c1 = t + 256;
        const int b0r = c0 >> 2, b0q = (c0 & 3) * 8;
        const int b1r = c1 >> 2, b1q = (c1 & 3) * 8;
        const size_t gb0 = (size_t)(j0 + b0r) * K + k0 + b0q;
        const size_t gb1 = (size_t)(j0 + b1r) * K + k0 + b1q;
        u16x8 vc0 = *(const u16x8*)(Bh + gb0);
        u16x8 vc1 = *(const u16x8*)(Bh + gb1);
        u16x8 vd0 = *(const u16x8*)(Bl + gb0);
        u16x8 vd1 = *(const u16x8*)(Bl + gb1);
        __syncthreads();
        *(u16x8*)&sAh[arow][akq] = va;
        *(u16x8*)&sAl[arow][akq] = vb;
        *(u16x8*)&sBh[b0r][b0q] = vc0;
        *(u16x8*)&sBh[b1r][b1q] = vc1;
        *(u16x8*)&sBl[b0r][b0q] = vd0;
        *(u16x8*)&sBl[b1r][b1q] = vd1;
        __syncthreads();
        s16x8 ah[2], al[2], bh[4], bl[4];
#pragma unroll
        for (int fi = 0; fi < 2; ++fi) {
            ah[fi] = *(const s16x8*)&sAh[wr * 32 + fi * 16 + lc][lr * 8];
            al[fi] = *(const s16x8*)&sAl[wr * 32 + fi * 16 + lc][lr * 8];
        }
#pragma unroll
        for (int fj = 0; fj < 4; ++fj) {
            bh[fj] = *(const s16x8*)&sBh[wc * 64 + fj * 16 + lc][lr * 8];
            bl[fj] = *(const s16x8*)&sBl[wc * 64 + fj * 16 + lc][lr * 8];
        }
#pragma unroll
        for (int fi = 0; fi < 2; ++fi)
#pragma unroll
            for (int fj = 0; fj < 4; ++fj) {
                acc[fi][fj] = mfma16(ah[fi], bh[fj], acc[fi][fj]);
                acc[fi][fj] = mfma16(ah[fi], bl[fj], acc[fi][fj]);
                acc[fi][fj] = mfma16(al[fi], bh[fj], acc[fi][fj]);
            }
    }

#pragma unroll
    for (int fi = 0; fi < 2; ++fi)
#pragma unroll
        for (int fj = 0; fj < 4; ++fj) {
            f32x4 d = acc[fi][fj];
#pragma unroll
            for (int r = 0; r < 4; ++r) {
                int i = i0 + wr * 32 + fi * 16 + lr * 4 + r;
                int j = j0 + wc * 64 + fj * 16 + lc;
                size_t o = (size_t)i * N + j;
                float vv = fmaxf(d[r], 0.f);
                if (EPI == 1) {
                    Cf[o] = vv;
                } else {
                    float m = b2f(Mulh[o]) + b2f(Mull[o]);
                    vv *= m;
                    unsigned int pp = split2(vv);
                    Ch[o] = (U16)pp; Cl[o] = (U16)(pp >> 16);
                }
            }
        }
}

extern "C" void kernel_launch(void* const* d_in, const int* in_sizes, int n_in,
                              void* d_out, int out_size, void* d_ws, size_t ws_size,
                              hipStream_t stream) {
    (void)in_sizes; (void)n_in; (void)out_size; (void)ws_size;
    const float* emb = (const float*)d_in[0];   // (B,T,d)
    const float* E   = (const float*)d_in[1];   // (d,n)
    const float* Dx  = (const float*)d_in[2];   // (n,d)
    const float* Dy  = (const float*)d_in[3];   // (n,d)
    float* out = (float*)d_out;                 // (B,T,d)

    char* wsb = (char*)d_ws;
    // split-bf16 input copies
    U16* embh = (U16*)(wsb + 0);         // 1 MB   (a f32 overlays embh+embl later)
    U16* embl = (U16*)(wsb + 1048576);   // 1 MB
    U16* Eh   = (U16*)(wsb + 2097152);   // 512 KB
    U16* El   = (U16*)(wsb + 2621440);
    U16* Dxh  = (U16*)(wsb + 3145728);
    U16* Dxl  = (U16*)(wsb + 3670016);
    U16* Dyh  = (U16*)(wsb + 4194304);
    U16* Dyl  = (U16*)(wsb + 4718592);
    U16* lnvTh = (U16*)(wsb + 5242880);  // 1 MB  (v f32 overlays lnvT later)
    U16* lnvTl = (U16*)(wsb + 6291456);  // 1 MB
    float* xu  = (float*)(wsb + 7340032);   // 8 MB  (yh/yl overlay later)
    float* S   = (float*)(wsb + 15728640);  // 8 KB
    float* rc  = (float*)(wsb + 15736832);  // 8 KB
    U16* xh    = (U16*)(wsb + 15745024);    // 4 MB
    U16* xl    = (U16*)(wsb + 19939328);    // 4 MB
    U16* Wh    = (U16*)(wsb + 24133632);    // 1 MB  (alnh overlays after use)
    U16* Wl    = (U16*)(wsb + 25182208);    // 1 MB  (alnl overlays after use)
    // overlays (non-overlapping lifetimes)
    float* a    = (float*)(wsb + 0);         // 2 MB over emb splits (dead post-GEMM a)
    U16* alnh   = Wh;                        // over W (dead post-GEMM a)
    U16* alnl   = Wl;
    U16* yh     = (U16*)(wsb + 7340032);     // over xu (dead post-xscan)
    U16* yl     = (U16*)(wsb + 11534336);
    float* v    = (float*)(wsb + 5242880);   // 2 MB over lnvT (dead post-GEMM a)

    // 1. split-convert inputs
    cvt_kernel<<<1280, 256, 0, stream>>>(emb, E, Dx, Dy,
        embh, embl, Eh, El, Dxh, Dxl, Dyh, Dyl);
    // 2. lnvT = LN(emb) transposed split (LDS transpose, coalesced)
    lnT_kernel<<<ROWS / 16, 256, 0, stream>>>(emb, lnvTh, lnvTl);
    // 3. xu = relu(emb @ Dx^T)   M=2048 N=1024 K=256   (64x128 tiles)
    mfma_nt128_kernel<1><<<dim3(NN / 128, ROWS / 64), 256, 0, stream>>>(
        embh, embl, Dxh, Dxl, xu, nullptr, nullptr, nullptr, nullptr, NN, DD);
    // 4. S = rowsum(xu)
    rowsum_kernel<<<ROWS / 4, 256, 0, stream>>>(xu, S);
    // 5. normalizer scan (LDS-resident, divide off the carry chain)
    cscan_kernel<<<1, 256, 0, stream>>>(S, rc);
    // 6. x scan -> split bf16
    xscan_kernel<<<BB * (NN / 16), 256, 0, stream>>>(xu, rc, xh, xl);
    // 7. W = mask . (X X^T)  batched  M=N=256 K=1024
    mfma_nt_kernel<3><<<dim3(TT / 64, TT / 64, BB), 256, 0, stream>>>(
        xh, xl, xh, xl, nullptr, Wh, Wl, TT, NN,
        (long long)TT * NN, (long long)TT * NN, (long long)TT * TT);
    // 8. a = W @ lnv  batched  M=256 N=256 K=256 (B = lnvT rows)
    mfma_nt_kernel<0><<<dim3(DD / 64, TT / 64, BB), 256, 0, stream>>>(
        Wh, Wl, lnvTh, lnvTl, a, nullptr, nullptr, DD, TT,
        (long long)TT * TT, (long long)DD * TT, (long long)TT * DD);
    // 9. aln = LN(a) split
    ln_kernel<1><<<ROWS / 4, 256, 0, stream>>>(a, nullptr, alnh, alnl);
    // 10. y = relu(aln @ Dy^T) * x -> split   M=2048 N=1024 K=256  (64x128)
    mfma_nt128_kernel<2><<<dim3(NN / 128, ROWS / 64), 256, 0, stream>>>(
        alnh, alnl, Dyh, Dyl, nullptr, yh, yl, xh, xl, NN, DD);
    // 11. v = y @ E^T   M=2048 N=256 K=1024
    mfma_nt_kernel<0><<<dim3(DD / 64, ROWS / 64, 1), 256, 0, stream>>>(
        yh, yl, Eh, El, v, nullptr, nullptr, DD, NN, 0, 0, 0);
    // 12. out = LN(v)
    ln_kernel<0><<<ROWS / 4, 256, 0, stream>>>(v, out, nullptr, nullptr);
}

// Round 7
// 75.500 us; speedup vs baseline: 3.4804x; 1.4945x over previous
//
#include <hip/hip_runtime.h>
#include <math.h>

// BDH recurrence, parallelized; all GEMMs single-fp16 operands, f32 accum.
//   xu = relu(emb @ Dx^T) (+fused rowsum)       MFMA GEMM 64x128 (f32 out)
//   c_t scalar scan (LDS) ; x chunked affine scan (fp16 x out)
//   W[t,s] = (s<t) 0.97^(t-1-s) * (x_t . x_s)   MFMA GEMM 64x64 + mask (f16 out)
//   a = W @ lnvT^T                              MFMA GEMM 64x64 (f32 out)
//   y = relu(LN(a) @ Dy^T) * x                  MFMA GEMM 64x128 (f16 out)
//   out = LN(y @ E^T)                           MFMA GEMM 64x64 split-K + LN

#define TT 256
#define BB 8
#define DD 256
#define NN 1024
#define ROWS (BB*TT)   // 2048

using f16   = _Float16;
using f16x4 = __attribute__((ext_vector_type(4))) _Float16;
using f16x8 = __attribute__((ext_vector_type(8))) _Float16;
using f32x4 = __attribute__((ext_vector_type(4))) float;

__device__ inline f32x4 mfma16(f16x8 a, f16x8 b, f32x4 c) {
    return __builtin_amdgcn_mfma_f32_16x16x32_f16(a, b, c, 0, 0, 0);
}

// ---------------- convert inputs to fp16 + LN-transpose of emb -------------
__launch_bounds__(256)
__global__ void cvtln_kernel(const float* __restrict__ emb, const float* __restrict__ E,
                             const float* __restrict__ Dx, const float* __restrict__ Dy,
                             f16* __restrict__ embf, f16* __restrict__ Ef,
                             f16* __restrict__ Dxf, f16* __restrict__ Dyf,
                             f16* __restrict__ lnvTf) {
    __shared__ f16 sT[256][24];
    if (blockIdx.x < 1280) {
        int base = (blockIdx.x * 256 + threadIdx.x) * 4;
        const float* s; f16* d; int loc;
        if      (base <  524288) { s = emb; d = embf; loc = base; }
        else if (base <  786432) { s = E;   d = Ef;   loc = base - 524288; }
        else if (base < 1048576) { s = Dx;  d = Dxf;  loc = base - 786432; }
        else                     { s = Dy;  d = Dyf;  loc = base - 1048576; }
        float4 v = *(const float4*)(s + loc);
        f16x4 h = {(f16)v.x, (f16)v.y, (f16)v.z, (f16)v.w};
        *(f16x4*)(d + loc) = h;
        return;
    }
    // LN(emb) transposed per batch: lnvTf[b][j][t]
    const int bx = blockIdx.x - 1280;
    const int b  = bx >> 4;
    const int t0 = (bx & 15) * 16;
    const int wave = threadIdx.x >> 6;
    const int lane = threadIdx.x & 63;
#pragma unroll
    for (int rr = 0; rr < 4; ++rr) {
        int tloc = wave * 4 + rr;
        const float* p = emb + ((size_t)b * TT + t0 + tloc) * DD;
        float4 v = *(const float4*)(p + lane * 4);
        float s  = v.x + v.y + v.z + v.w;
        float s2 = v.x*v.x + v.y*v.y + v.z*v.z + v.w*v.w;
#pragma unroll
        for (int o = 32; o; o >>= 1) {
            s  += __shfl_xor(s,  o, 64);
            s2 += __shfl_xor(s2, o, 64);
        }
        float m   = s * (1.0f / 256.0f);
        float var = s2 * (1.0f / 256.0f) - m * m;
        float sc  = rsqrtf(var + 1e-5f);
        sT[lane * 4 + 0][tloc] = (f16)((v.x - m) * sc);
        sT[lane * 4 + 1][tloc] = (f16)((v.y - m) * sc);
        sT[lane * 4 + 2][tloc] = (f16)((v.z - m) * sc);
        sT[lane * 4 + 3][tloc] = (f16)((v.w - m) * sc);
    }
    __syncthreads();
    int j = threadIdx.x;
    size_t o = ((size_t)b * DD + j) * TT + t0;
    *(f16x8*)(lnvTf + o)     = *(const f16x8*)&sT[j][0];
    *(f16x8*)(lnvTf + o + 8) = *(const f16x8*)&sT[j][8];
}

// ---------------- LayerNorm rows of 256 ------------------------------------
// MODE 0: f32 out. MODE 1: f16 out. MODE 2: f32 out of LN(in + in2).
template <int MODE>
__launch_bounds__(256)
__global__ void ln_kernel(const float* __restrict__ in, const float* __restrict__ in2,
                          float* __restrict__ outf, f16* __restrict__ outh) {
    int wave = threadIdx.x >> 6;
    int lane = threadIdx.x & 63;
    int row  = blockIdx.x * 4 + wave;
    const float* p = in + (size_t)row * DD;
    float4 v = *(const float4*)(p + lane * 4);
    if (MODE == 2) {
        float4 w = *(const float4*)(in2 + (size_t)row * DD + lane * 4);
        v.x += w.x; v.y += w.y; v.z += w.z; v.w += w.w;
    }
    float s  = v.x + v.y + v.z + v.w;
    float s2 = v.x*v.x + v.y*v.y + v.z*v.z + v.w*v.w;
#pragma unroll
    for (int o = 32; o; o >>= 1) {
        s  += __shfl_xor(s,  o, 64);
        s2 += __shfl_xor(s2, o, 64);
    }
    float m   = s * (1.0f / 256.0f);
    float var = s2 * (1.0f / 256.0f) - m * m;
    float sc  = rsqrtf(var + 1e-5f);
    float r4[4] = {(v.x - m) * sc, (v.y - m) * sc, (v.z - m) * sc, (v.w - m) * sc};
    if (MODE == 1) {
        f16x4 h = {(f16)r4[0], (f16)r4[1], (f16)r4[2], (f16)r4[3]};
        *(f16x4*)(outh + (size_t)row * DD + lane * 4) = h;
    } else {
        float4 o4 = {r4[0], r4[1], r4[2], r4[3]};
        *(float4*)(outf + (size_t)row * DD + lane * 4) = o4;
    }
}

// ---------------- normalizer scan, LDS-resident ----------------------------
// Spart[8][ROWS] partial row sums from the xu GEMM; reduce, scan, reciprocal.
__launch_bounds__(256)
__global__ void cscan_kernel(const float* __restrict__ Spart, float* __restrict__ rc) {
    __shared__ float sS[BB][TT + 1];
    __shared__ float sUS[BB][TT + 1];
    const int tid = threadIdx.x;
#pragma unroll
    for (int i = 0; i < ROWS / 256; ++i) {
        int idx = tid + i * 256;
        float s = 0.f;
#pragma unroll
        for (int g = 0; g < 8; ++g) s += Spart[(size_t)g * ROWS + idx];
        sS[idx >> 8][idx & 255] = s;
    }
    __syncthreads();
    if (tid < BB) {
        float sigma = 0.f;
        for (int t = 0; t < TT; ++t) {
            float us = fmaf(0.97f, sigma, sS[tid][t]);
            sUS[tid][t] = us;
            sigma = (us >= 1e-12f) ? 1.0f : us * 1e12f;
        }
    }
    __syncthreads();
#pragma unroll
    for (int i = 0; i < ROWS / 256; ++i) {
        int idx = tid + i * 256;
        rc[idx] = 1.0f / fmaxf(sUS[idx >> 8][idx & 255], 1e-12f);
    }
}

// ---------------- chunked x scan; writes fp16 x -----------------------------
__launch_bounds__(256)
__global__ void xscan_kernel(const float* __restrict__ xu, const float* __restrict__ rc,
                             f16* __restrict__ xf) {
    __shared__ float Gs[16][16], Hs[16][16], Cs[16][16];
    const int b    = blockIdx.x >> 6;
    const int jgrp = blockIdx.x & 63;
    const int tid  = threadIdx.x;
    const int ck   = tid >> 4;
    const int jl   = tid & 15;
    const int j    = jgrp * 16 + jl;
    const size_t base = ((size_t)b * TT + ck * 16) * NN + j;
    float xur[16], rcr[16];
#pragma unroll
    for (int i = 0; i < 16; ++i) xur[i] = xu[base + (size_t)i * NN];
#pragma unroll
    for (int i = 0; i < 16; ++i) rcr[i] = rc[b * TT + ck * 16 + i];
    float xs = 0.f, G = 1.f;
#pragma unroll
    for (int i = 0; i < 16; ++i) {
        xs = fmaf(0.97f, xs, xur[i]) * rcr[i];
        G *= 0.97f * rcr[i];
    }
    Gs[ck][jl] = G;
    Hs[ck][jl] = xs;
    __syncthreads();
    if (tid < 16) {
        float cr = 0.f;
        Cs[0][tid] = 0.f;
#pragma unroll
        for (int cc = 0; cc < 15; ++cc) {
            cr = fmaf(Gs[cc][tid], cr, Hs[cc][tid]);
            Cs[cc + 1][tid] = cr;
        }
    }
    __syncthreads();
    xs = Cs[ck][jl];
#pragma unroll
    for (int i = 0; i < 16; ++i) {
        xs = fmaf(0.97f, xs, xur[i]) * rcr[i];
        xf[base + (size_t)i * NN] = (f16)xs;
    }
}

// ---------------- fp16 MFMA NT GEMM, 64x64 tile ----------------------------
// C[i,j] = sum_k A[i,k]*B[j,k].  4 waves x 32x32.  ld = row stride, Kloop<=ld.
// EPI: 0 none->f32 ; 3 decay-mask->f16.
template <int EPI>
__launch_bounds__(256)
__global__ void g64_kernel(const f16* __restrict__ A, const f16* __restrict__ B,
                           float* __restrict__ Cf, f16* __restrict__ Ch,
                           int N, int ld, int Kloop,
                           long long sA_, long long sB_, long long sC_) {
    const int z = blockIdx.z;
    A += (size_t)z * sA_; B += (size_t)z * sB_;
    if (EPI == 0) Cf += (size_t)z * sC_; else Ch += (size_t)z * sC_;
    const int i0 = blockIdx.y * 64, j0 = blockIdx.x * 64;
    const int t = threadIdx.x, lane = t & 63, wid = t >> 6;
    const int wr = wid >> 1, wc = wid & 1;
    const int lr = lane >> 4, lc = lane & 15;
    const float L2D = -0.043943348f;  // log2(0.97)

    if (EPI == 3 && j0 > i0) {        // fully-masked tile: zero-fill
#pragma unroll
        for (int fi = 0; fi < 2; ++fi)
#pragma unroll
            for (int fj = 0; fj < 2; ++fj)
#pragma unroll
                for (int r = 0; r < 4; ++r) {
                    int i = i0 + wr * 32 + fi * 16 + lr * 4 + r;
                    int j = j0 + wc * 32 + fj * 16 + lc;
                    Ch[(size_t)i * N + j] = (f16)0.f;
                }
        return;
    }

    __shared__ __align__(16) f16 sA[64][40], sB[64][40];
    const int srow = t >> 2, skq = (t & 3) * 8;
    f32x4 acc[2][2];
    const f32x4 z4 = {0.f, 0.f, 0.f, 0.f};
    acc[0][0] = z4; acc[0][1] = z4; acc[1][0] = z4; acc[1][1] = z4;

    for (int k0 = 0; k0 < Kloop; k0 += 32) {
        f16x8 va = *(const f16x8*)(A + (size_t)(i0 + srow) * ld + k0 + skq);
        f16x8 vb = *(const f16x8*)(B + (size_t)(j0 + srow) * ld + k0 + skq);
        __syncthreads();
        *(f16x8*)&sA[srow][skq] = va;
        *(f16x8*)&sB[srow][skq] = vb;
        __syncthreads();
        f16x8 ah0 = *(const f16x8*)&sA[wr * 32 + lc][lr * 8];
        f16x8 ah1 = *(const f16x8*)&sA[wr * 32 + 16 + lc][lr * 8];
        f16x8 bh0 = *(const f16x8*)&sB[wc * 32 + lc][lr * 8];
        f16x8 bh1 = *(const f16x8*)&sB[wc * 32 + 16 + lc][lr * 8];
        acc[0][0] = mfma16(ah0, bh0, acc[0][0]);
        acc[0][1] = mfma16(ah0, bh1, acc[0][1]);
        acc[1][0] = mfma16(ah1, bh0, acc[1][0]);
        acc[1][1] = mfma16(ah1, bh1, acc[1][1]);
    }

#pragma unroll
    for (int fi = 0; fi < 2; ++fi)
#pragma unroll
        for (int fj = 0; fj < 2; ++fj) {
            f32x4 d = acc[fi][fj];
#pragma unroll
            for (int r = 0; r < 4; ++r) {
                int i = i0 + wr * 32 + fi * 16 + lr * 4 + r;
                int j = j0 + wc * 32 + fj * 16 + lc;
                size_t o = (size_t)i * N + j;
                if (EPI == 0) {
                    Cf[o] = d[r];
                } else {
                    float w = 0.f;
                    if (j < i) w = exp2f((float)(i - 1 - j) * L2D) * d[r];
                    Ch[o] = (f16)w;
                }
            }
        }
}

// ---------------- fp16 MFMA NT GEMM, 64x128 tile ---------------------------
// 4 waves x 32x64.  EPI: 1 relu->f32 + Spart row-partials ; 2 relu*Mul->f16.
template <int EPI>
__launch_bounds__(256)
__global__ void g128_kernel(const f16* __restrict__ A, const f16* __restrict__ B,
                            float* __restrict__ Cf, f16* __restrict__ Ch,
                            const f16* __restrict__ Mul, float* __restrict__ Spart,
                            int N, int K) {
    const int i0 = blockIdx.y * 64, j0 = blockIdx.x * 128;
    const int t = threadIdx.x, lane = t & 63, wid = t >> 6;
    const int wr = wid >> 1, wc = wid & 1;
    const int lr = lane >> 4, lc = lane & 15;

    __shared__ __align__(16) f16 sA[64][40], sB[128][40];
    __shared__ float ssum[64][2];
    const int arow = t >> 2, akq = (t & 3) * 8;
    f32x4 acc[2][4];
    const f32x4 z4 = {0.f, 0.f, 0.f, 0.f};
#pragma unroll
    for (int fi = 0; fi < 2; ++fi)
#pragma unroll
        for (int fj = 0; fj < 4; ++fj) acc[fi][fj] = z4;

    for (int k0 = 0; k0 < K; k0 += 32) {
        f16x8 va  = *(const f16x8*)(A + (size_t)(i0 + arow) * K + k0 + akq);
        f16x8 vb0 = *(const f16x8*)(B + (size_t)(j0 + arow) * K + k0 + akq);
        f16x8 vb1 = *(const f16x8*)(B + (size_t)(j0 + 64 + arow) * K + k0 + akq);
        __syncthreads();
        *(f16x8*)&sA[arow][akq] = va;
        *(f16x8*)&sB[arow][akq] = vb0;
        *(f16x8*)&sB[64 + arow][akq] = vb1;
        __syncthreads();
        f16x8 ah[2], bh[4];
#pragma unroll
        for (int fi = 0; fi < 2; ++fi)
            ah[fi] = *(const f16x8*)&sA[wr * 32 + fi * 16 + lc][lr * 8];
#pragma unroll
        for (int fj = 0; fj < 4; ++fj)
            bh[fj] = *(const f16x8*)&sB[wc * 64 + fj * 16 + lc][lr * 8];
#pragma unroll
        for (int fi = 0; fi < 2; ++fi)
#pragma unroll
            for (int fj = 0; fj < 4; ++fj)
                acc[fi][fj] = mfma16(ah[fi], bh[fj], acc[fi][fj]);
    }

    float rs[2][4] = {};
#pragma unroll
    for (int fi = 0; fi < 2; ++fi)
#pragma unroll
        for (int fj = 0; fj < 4; ++fj) {
            f32x4 d = acc[fi][fj];
#pragma unroll
            for (int r = 0; r < 4; ++r) {
                int i = i0 + wr * 32 + fi * 16 + lr * 4 + r;
                int j = j0 + wc * 64 + fj * 16 + lc;
                size_t o = (size_t)i * N + j;
                float vv = fmaxf(d[r], 0.f);
                if (EPI == 1) {
                    Cf[o] = vv;
                    rs[fi][r] += vv;
                } else {
                    vv *= (float)Mul[o];
                    Ch[o] = (f16)vv;
                }
            }
        }
    if (EPI == 1) {
#pragma unroll
        for (int fi = 0; fi < 2; ++fi)
#pragma unroll
            for (int r = 0; r < 4; ++r) {
                float v = rs[fi][r];
#pragma unroll
                for (int m = 1; m < 16; m <<= 1) v += __shfl_xor(v, m, 64);
                if (lc == 0) ssum[wr * 32 + fi * 16 + lr * 4 + r][wc] = v;
            }
        __syncthreads();
        if (t < 64) Spart[(size_t)blockIdx.x * ROWS + i0 + t] = ssum[t][0] + ssum[t][1];
    }
}

extern "C" void kernel_launch(void* const* d_in, const int* in_sizes, int n_in,
                              void* d_out, int out_size, void* d_ws, size_t ws_size,
                              hipStream_t stream) {
    (void)in_sizes; (void)n_in; (void)out_size; (void)ws_size;
    const float* emb = (const float*)d_in[0];   // (B,T,d)
    const float* E   = (const float*)d_in[1];   // (d,n)
    const float* Dx  = (const float*)d_in[2];   // (n,d)
    const float* Dy  = (const float*)d_in[3];   // (n,d)
    float* out = (float*)d_out;                 // (B,T,d)

    char* wsb = (char*)d_ws;
    f16*   embf  = (f16*)(wsb + 0);          // 1 MB
    f16*   Ef    = (f16*)(wsb + 1048576);    // 512 KB
    f16*   Dxf   = (f16*)(wsb + 1572864);    // 512 KB
    f16*   Dyf   = (f16*)(wsb + 2097152);    // 512 KB
    f16*   lnvTf = (f16*)(wsb + 2621440);    // 1 MB   [b][j][t]
    f16*   xf    = (f16*)(wsb + 3670016);    // 4 MB   [b][t][n]
    f16*   Wf    = (f16*)(wsb + 7864320);    // 1 MB   [b][t][s]
    f16*   alnf  = (f16*)(wsb + 8912896);    // 1 MB
    f16*   yf    = (f16*)(wsb + 9961472);    // 4 MB
    float* xu    = (float*)(wsb + 14155776); // 8 MB
    float* a     = (float*)(wsb + 22544384); // 2 MB
    float* vpart = (float*)(wsb + 24641536); // 4 MB (2 x ROWS*DD)
    float* Spart = (float*)(wsb + 28835840); // 64 KB (8 x ROWS)
    float* rc    = (float*)(wsb + 28901376); // 8 KB

    // 1. fp16-convert inputs + LN(emb) transposed
    cvtln_kernel<<<1280 + ROWS / 16, 256, 0, stream>>>(
        emb, E, Dx, Dy, embf, Ef, Dxf, Dyf, lnvTf);
    // 2. xu = relu(emb @ Dx^T) + fused row-sum partials   M=2048 N=1024 K=256
    g128_kernel<1><<<dim3(NN / 128, ROWS / 64), 256, 0, stream>>>(
        embf, Dxf, xu, nullptr, nullptr, Spart, NN, DD);
    // 3. normalizer scan (reduce Spart, LDS serial scan, reciprocals)
    cscan_kernel<<<1, 256, 0, stream>>>(Spart, rc);
    // 4. x scan -> fp16
    xscan_kernel<<<BB * (NN / 16), 256, 0, stream>>>(xu, rc, xf);
    // 5. W = mask . (X X^T)  batched  M=N=256 K=1024
    g64_kernel<3><<<dim3(TT / 64, TT / 64, BB), 256, 0, stream>>>(
        xf, xf, nullptr, Wf, TT, NN, NN,
        (long long)TT * NN, (long long)TT * NN, (long long)TT * TT);
    // 6. a = W @ lnv  batched  M=256 N=256 K=256
    g64_kernel<0><<<dim3(DD / 64, TT / 64, BB), 256, 0, stream>>>(
        Wf, lnvTf, a, nullptr, DD, TT, TT,
        (long long)TT * TT, (long long)DD * TT, (long long)TT * DD);
    // 7. aln = LN(a) -> fp16
    ln_kernel<1><<<ROWS / 4, 256, 0, stream>>>(a, nullptr, nullptr, alnf);
    // 8. y = relu(aln @ Dy^T) * x -> fp16   M=2048 N=1024 K=256
    g128_kernel<2><<<dim3(NN / 128, ROWS / 64), 256, 0, stream>>>(
        alnf, Dyf, nullptr, yf, xf, nullptr, NN, DD);
    // 9. vpart[z] = y @ E^T (K-half z)   M=2048 N=256 K=512 x2
    g64_kernel<0><<<dim3(DD / 64, ROWS / 64, 2), 256, 0, stream>>>(
        yf, Ef, vpart, nullptr, DD, NN, 512,
        512LL, 512LL, (long long)ROWS * DD);
    // 10. out = LN(vpart0 + vpart1)
    ln_kernel<2><<<ROWS / 4, 256, 0, stream>>>(
        vpart, vpart + (size_t)ROWS * DD, out, nullptr);
}

// Round 8
// 70.401 us; speedup vs baseline: 3.7325x; 1.0724x over previous
//
#include <hip/hip_runtime.h>
#include <math.h>

// BDH recurrence, parallelized; all GEMMs single-fp16 operands, f32 accum.
// GEMMs use 2-phase double-buffered LDS staging (prefetch k+1 to regs while
// computing k from LDS; one barrier per K-step) to hide global latency.
//   xu = relu(emb @ Dx^T) (+fused rowsum)       MFMA GEMM 64x128 (f32 out)
//   c_t scalar scan (LDS) ; x chunked affine scan (fp16 x out)
//   W[t,s] = (s<t) 0.97^(t-1-s) * (x_t . x_s)   MFMA GEMM 64x64 + mask (f16 out)
//   a = W @ lnvT^T                              MFMA GEMM 64x64 (f32 out)
//   y = relu(LN(a) @ Dy^T) * x                  MFMA GEMM 64x128 (f16 out)
//   out = LN(y @ E^T)                           MFMA GEMM 64x64 split-K + LN

#define TT 256
#define BB 8
#define DD 256
#define NN 1024
#define ROWS (BB*TT)   // 2048

using f16   = _Float16;
using f16x4 = __attribute__((ext_vector_type(4))) _Float16;
using f16x8 = __attribute__((ext_vector_type(8))) _Float16;
using f32x4 = __attribute__((ext_vector_type(4))) float;

__device__ inline f32x4 mfma16(f16x8 a, f16x8 b, f32x4 c) {
    return __builtin_amdgcn_mfma_f32_16x16x32_f16(a, b, c, 0, 0, 0);
}

// ---------------- convert inputs to fp16 + LN-transpose of emb -------------
__launch_bounds__(256)
__global__ void cvtln_kernel(const float* __restrict__ emb, const float* __restrict__ E,
                             const float* __restrict__ Dx, const float* __restrict__ Dy,
                             f16* __restrict__ embf, f16* __restrict__ Ef,
                             f16* __restrict__ Dxf, f16* __restrict__ Dyf,
                             f16* __restrict__ lnvTf) {
    __shared__ f16 sT[256][24];
    if (blockIdx.x < 1280) {
        int base = (blockIdx.x * 256 + threadIdx.x) * 4;
        const float* s; f16* d; int loc;
        if      (base <  524288) { s = emb; d = embf; loc = base; }
        else if (base <  786432) { s = E;   d = Ef;   loc = base - 524288; }
        else if (base < 1048576) { s = Dx;  d = Dxf;  loc = base - 786432; }
        else                     { s = Dy;  d = Dyf;  loc = base - 1048576; }
        float4 v = *(const float4*)(s + loc);
        f16x4 h = {(f16)v.x, (f16)v.y, (f16)v.z, (f16)v.w};
        *(f16x4*)(d + loc) = h;
        return;
    }
    // LN(emb) transposed per batch: lnvTf[b][j][t]
    const int bx = blockIdx.x - 1280;
    const int b  = bx >> 4;
    const int t0 = (bx & 15) * 16;
    const int wave = threadIdx.x >> 6;
    const int lane = threadIdx.x & 63;
#pragma unroll
    for (int rr = 0; rr < 4; ++rr) {
        int tloc = wave * 4 + rr;
        const float* p = emb + ((size_t)b * TT + t0 + tloc) * DD;
        float4 v = *(const float4*)(p + lane * 4);
        float s  = v.x + v.y + v.z + v.w;
        float s2 = v.x*v.x + v.y*v.y + v.z*v.z + v.w*v.w;
#pragma unroll
        for (int o = 32; o; o >>= 1) {
            s  += __shfl_xor(s,  o, 64);
            s2 += __shfl_xor(s2, o, 64);
        }
        float m   = s * (1.0f / 256.0f);
        float var = s2 * (1.0f / 256.0f) - m * m;
        float sc  = rsqrtf(var + 1e-5f);
        sT[lane * 4 + 0][tloc] = (f16)((v.x - m) * sc);
        sT[lane * 4 + 1][tloc] = (f16)((v.y - m) * sc);
        sT[lane * 4 + 2][tloc] = (f16)((v.z - m) * sc);
        sT[lane * 4 + 3][tloc] = (f16)((v.w - m) * sc);
    }
    __syncthreads();
    int j = threadIdx.x;
    size_t o = ((size_t)b * DD + j) * TT + t0;
    *(f16x8*)(lnvTf + o)     = *(const f16x8*)&sT[j][0];
    *(f16x8*)(lnvTf + o + 8) = *(const f16x8*)&sT[j][8];
}

// ---------------- LayerNorm rows of 256 ------------------------------------
// MODE 0: f32 out. MODE 1: f16 out. MODE 2: f32 out of LN(in + in2).
template <int MODE>
__launch_bounds__(256)
__global__ void ln_kernel(const float* __restrict__ in, const float* __restrict__ in2,
                          float* __restrict__ outf, f16* __restrict__ outh) {
    int wave = threadIdx.x >> 6;
    int lane = threadIdx.x & 63;
    int row  = blockIdx.x * 4 + wave;
    const float* p = in + (size_t)row * DD;
    float4 v = *(const float4*)(p + lane * 4);
    if (MODE == 2) {
        float4 w = *(const float4*)(in2 + (size_t)row * DD + lane * 4);
        v.x += w.x; v.y += w.y; v.z += w.z; v.w += w.w;
    }
    float s  = v.x + v.y + v.z + v.w;
    float s2 = v.x*v.x + v.y*v.y + v.z*v.z + v.w*v.w;
#pragma unroll
    for (int o = 32; o; o >>= 1) {
        s  += __shfl_xor(s,  o, 64);
        s2 += __shfl_xor(s2, o, 64);
    }
    float m   = s * (1.0f / 256.0f);
    float var = s2 * (1.0f / 256.0f) - m * m;
    float sc  = rsqrtf(var + 1e-5f);
    float r4[4] = {(v.x - m) * sc, (v.y - m) * sc, (v.z - m) * sc, (v.w - m) * sc};
    if (MODE == 1) {
        f16x4 h = {(f16)r4[0], (f16)r4[1], (f16)r4[2], (f16)r4[3]};
        *(f16x4*)(outh + (size_t)row * DD + lane * 4) = h;
    } else {
        float4 o4 = {r4[0], r4[1], r4[2], r4[3]};
        *(float4*)(outf + (size_t)row * DD + lane * 4) = o4;
    }
}

// ---------------- normalizer scan, LDS-resident ----------------------------
__launch_bounds__(256)
__global__ void cscan_kernel(const float* __restrict__ Spart, float* __restrict__ rc) {
    __shared__ float sS[BB][TT + 1];
    __shared__ float sUS[BB][TT + 1];
    const int tid = threadIdx.x;
#pragma unroll
    for (int i = 0; i < ROWS / 256; ++i) {
        int idx = tid + i * 256;
        float s = 0.f;
#pragma unroll
        for (int g = 0; g < 8; ++g) s += Spart[(size_t)g * ROWS + idx];
        sS[idx >> 8][idx & 255] = s;
    }
    __syncthreads();
    if (tid < BB) {
        float sigma = 0.f;
        for (int t = 0; t < TT; ++t) {
            float us = fmaf(0.97f, sigma, sS[tid][t]);
            sUS[tid][t] = us;
            sigma = (us >= 1e-12f) ? 1.0f : us * 1e12f;
        }
    }
    __syncthreads();
#pragma unroll
    for (int i = 0; i < ROWS / 256; ++i) {
        int idx = tid + i * 256;
        rc[idx] = 1.0f / fmaxf(sUS[idx >> 8][idx & 255], 1e-12f);
    }
}

// ---------------- chunked x scan; writes fp16 x -----------------------------
__launch_bounds__(256)
__global__ void xscan_kernel(const float* __restrict__ xu, const float* __restrict__ rc,
                             f16* __restrict__ xf) {
    __shared__ float Gs[16][16], Hs[16][16], Cs[16][16];
    const int b    = blockIdx.x >> 6;
    const int jgrp = blockIdx.x & 63;
    const int tid  = threadIdx.x;
    const int ck   = tid >> 4;
    const int jl   = tid & 15;
    const int j    = jgrp * 16 + jl;
    const size_t base = ((size_t)b * TT + ck * 16) * NN + j;
    float xur[16], rcr[16];
#pragma unroll
    for (int i = 0; i < 16; ++i) xur[i] = xu[base + (size_t)i * NN];
#pragma unroll
    for (int i = 0; i < 16; ++i) rcr[i] = rc[b * TT + ck * 16 + i];
    float xs = 0.f, G = 1.f;
#pragma unroll
    for (int i = 0; i < 16; ++i) {
        xs = fmaf(0.97f, xs, xur[i]) * rcr[i];
        G *= 0.97f * rcr[i];
    }
    Gs[ck][jl] = G;
    Hs[ck][jl] = xs;
    __syncthreads();
    if (tid < 16) {
        float cr = 0.f;
        Cs[0][tid] = 0.f;
#pragma unroll
        for (int cc = 0; cc < 15; ++cc) {
            cr = fmaf(Gs[cc][tid], cr, Hs[cc][tid]);
            Cs[cc + 1][tid] = cr;
        }
    }
    __syncthreads();
    xs = Cs[ck][jl];
#pragma unroll
    for (int i = 0; i < 16; ++i) {
        xs = fmaf(0.97f, xs, xur[i]) * rcr[i];
        xf[base + (size_t)i * NN] = (f16)xs;
    }
}

// ---------------- fp16 MFMA NT GEMM, 64x64 tile, double-buffered -----------
// C[i,j] = sum_k A[i,k]*B[j,k].  4 waves x 32x32.  ld = row stride, Kloop<=ld.
// EPI: 0 none->f32 ; 3 decay-mask->f16.
template <int EPI>
__launch_bounds__(256)
__global__ void g64_kernel(const f16* __restrict__ A, const f16* __restrict__ B,
                           float* __restrict__ Cf, f16* __restrict__ Ch,
                           int N, int ld, int Kloop,
                           long long sA_, long long sB_, long long sC_) {
    const int z = blockIdx.z;
    A += (size_t)z * sA_; B += (size_t)z * sB_;
    if (EPI == 0) Cf += (size_t)z * sC_; else Ch += (size_t)z * sC_;
    const int i0 = blockIdx.y * 64, j0 = blockIdx.x * 64;
    const int t = threadIdx.x, lane = t & 63, wid = t >> 6;
    const int wr = wid >> 1, wc = wid & 1;
    const int lr = lane >> 4, lc = lane & 15;
    const float L2D = -0.043943348f;  // log2(0.97)

    if (EPI == 3 && j0 > i0) {        // fully-masked tile: zero-fill
#pragma unroll
        for (int fi = 0; fi < 2; ++fi)
#pragma unroll
            for (int fj = 0; fj < 2; ++fj)
#pragma unroll
                for (int r = 0; r < 4; ++r) {
                    int i = i0 + wr * 32 + fi * 16 + lr * 4 + r;
                    int j = j0 + wc * 32 + fj * 16 + lc;
                    Ch[(size_t)i * N + j] = (f16)0.f;
                }
        return;
    }

    __shared__ __align__(16) f16 sA[2][64][40], sB[2][64][40];
    const int srow = t >> 2, skq = (t & 3) * 8;
    f32x4 acc[2][2];
    const f32x4 z4 = {0.f, 0.f, 0.f, 0.f};
    acc[0][0] = z4; acc[0][1] = z4; acc[1][0] = z4; acc[1][1] = z4;

    const int NT = Kloop / 32;
    const f16* pa = A + (size_t)(i0 + srow) * ld + skq;
    const f16* pb = B + (size_t)(j0 + srow) * ld + skq;
    f16x8 va = *(const f16x8*)(pa);
    f16x8 vb = *(const f16x8*)(pb);
    *(f16x8*)&sA[0][srow][skq] = va;
    *(f16x8*)&sB[0][srow][skq] = vb;
    __syncthreads();
    int cur = 0;
    for (int kt = 0; kt < NT; ++kt) {
        if (kt + 1 < NT) {
            va = *(const f16x8*)(pa + (kt + 1) * 32);
            vb = *(const f16x8*)(pb + (kt + 1) * 32);
        }
        f16x8 ah0 = *(const f16x8*)&sA[cur][wr * 32 + lc][lr * 8];
        f16x8 ah1 = *(const f16x8*)&sA[cur][wr * 32 + 16 + lc][lr * 8];
        f16x8 bh0 = *(const f16x8*)&sB[cur][wc * 32 + lc][lr * 8];
        f16x8 bh1 = *(const f16x8*)&sB[cur][wc * 32 + 16 + lc][lr * 8];
        acc[0][0] = mfma16(ah0, bh0, acc[0][0]);
        acc[0][1] = mfma16(ah0, bh1, acc[0][1]);
        acc[1][0] = mfma16(ah1, bh0, acc[1][0]);
        acc[1][1] = mfma16(ah1, bh1, acc[1][1]);
        if (kt + 1 < NT) {
            *(f16x8*)&sA[cur ^ 1][srow][skq] = va;
            *(f16x8*)&sB[cur ^ 1][srow][skq] = vb;
            __syncthreads();
            cur ^= 1;
        }
    }

#pragma unroll
    for (int fi = 0; fi < 2; ++fi)
#pragma unroll
        for (int fj = 0; fj < 2; ++fj) {
            f32x4 d = acc[fi][fj];
#pragma unroll
            for (int r = 0; r < 4; ++r) {
                int i = i0 + wr * 32 + fi * 16 + lr * 4 + r;
                int j = j0 + wc * 32 + fj * 16 + lc;
                size_t o = (size_t)i * N + j;
                if (EPI == 0) {
                    Cf[o] = d[r];
                } else {
                    float w = 0.f;
                    if (j < i) w = exp2f((float)(i - 1 - j) * L2D) * d[r];
                    Ch[o] = (f16)w;
                }
            }
        }
}

// ---------------- fp16 MFMA NT GEMM, 64x128 tile, double-buffered ----------
// 4 waves x 32x64.  EPI: 1 relu->f32 + Spart row-partials ; 2 relu*Mul->f16.
template <int EPI>
__launch_bounds__(256)
__global__ void g128_kernel(const f16* __restrict__ A, const f16* __restrict__ B,
                            float* __restrict__ Cf, f16* __restrict__ Ch,
                            const f16* __restrict__ Mul, float* __restrict__ Spart,
                            int N, int K) {
    const int i0 = blockIdx.y * 64, j0 = blockIdx.x * 128;
    const int t = threadIdx.x, lane = t & 63, wid = t >> 6;
    const int wr = wid >> 1, wc = wid & 1;
    const int lr = lane >> 4, lc = lane & 15;

    __shared__ __align__(16) f16 sA[2][64][40], sB[2][128][40];
    __shared__ float ssum[64][2];
    const int arow = t >> 2, akq = (t & 3) * 8;
    f32x4 acc[2][4];
    const f32x4 z4 = {0.f, 0.f, 0.f, 0.f};
#pragma unroll
    for (int fi = 0; fi < 2; ++fi)
#pragma unroll
        for (int fj = 0; fj < 4; ++fj) acc[fi][fj] = z4;

    const int NT = K / 32;
    const f16* pa  = A + (size_t)(i0 + arow) * K + akq;
    const f16* pb0 = B + (size_t)(j0 + arow) * K + akq;
    const f16* pb1 = B + (size_t)(j0 + 64 + arow) * K + akq;
    f16x8 va  = *(const f16x8*)(pa);
    f16x8 vb0 = *(const f16x8*)(pb0);
    f16x8 vb1 = *(const f16x8*)(pb1);
    *(f16x8*)&sA[0][arow][akq] = va;
    *(f16x8*)&sB[0][arow][akq] = vb0;
    *(f16x8*)&sB[0][64 + arow][akq] = vb1;
    __syncthreads();
    int cur = 0;
    for (int kt = 0; kt < NT; ++kt) {
        if (kt + 1 < NT) {
            va  = *(const f16x8*)(pa  + (kt + 1) * 32);
            vb0 = *(const f16x8*)(pb0 + (kt + 1) * 32);
            vb1 = *(const f16x8*)(pb1 + (kt + 1) * 32);
        }
        f16x8 ah[2], bh[4];
#pragma unroll
        for (int fi = 0; fi < 2; ++fi)
            ah[fi] = *(const f16x8*)&sA[cur][wr * 32 + fi * 16 + lc][lr * 8];
#pragma unroll
        for (int fj = 0; fj < 4; ++fj)
            bh[fj] = *(const f16x8*)&sB[cur][wc * 64 + fj * 16 + lc][lr * 8];
#pragma unroll
        for (int fi = 0; fi < 2; ++fi)
#pragma unroll
            for (int fj = 0; fj < 4; ++fj)
                acc[fi][fj] = mfma16(ah[fi], bh[fj], acc[fi][fj]);
        if (kt + 1 < NT) {
            *(f16x8*)&sA[cur ^ 1][arow][akq] = va;
            *(f16x8*)&sB[cur ^ 1][arow][akq] = vb0;
            *(f16x8*)&sB[cur ^ 1][64 + arow][akq] = vb1;
            __syncthreads();
            cur ^= 1;
        }
    }

    float rs[2][4] = {};
#pragma unroll
    for (int fi = 0; fi < 2; ++fi)
#pragma unroll
        for (int fj = 0; fj < 4; ++fj) {
            f32x4 d = acc[fi][fj];
#pragma unroll
            for (int r = 0; r < 4; ++r) {
                int i = i0 + wr * 32 + fi * 16 + lr * 4 + r;
                int j = j0 + wc * 64 + fj * 16 + lc;
                size_t o = (size_t)i * N + j;
                float vv = fmaxf(d[r], 0.f);
                if (EPI == 1) {
                    Cf[o] = vv;
                    rs[fi][r] += vv;
                } else {
                    vv *= (float)Mul[o];
                    Ch[o] = (f16)vv;
                }
            }
        }
    if (EPI == 1) {
#pragma unroll
        for (int fi = 0; fi < 2; ++fi)
#pragma unroll
            for (int r = 0; r < 4; ++r) {
                float v = rs[fi][r];
#pragma unroll
                for (int m = 1; m < 16; m <<= 1) v += __shfl_xor(v, m, 64);
                if (lc == 0) ssum[wr * 32 + fi * 16 + lr * 4 + r][wc] = v;
            }
        __syncthreads();
        if (t < 64) Spart[(size_t)blockIdx.x * ROWS + i0 + t] = ssum[t][0] + ssum[t][1];
    }
}

extern "C" void kernel_launch(void* const* d_in, const int* in_sizes, int n_in,
                              void* d_out, int out_size, void* d_ws, size_t ws_size,
                              hipStream_t stream) {
    (void)in_sizes; (void)n_in; (void)out_size; (void)ws_size;
    const float* emb = (const float*)d_in[0];   // (B,T,d)
    const float* E   = (const float*)d_in[1];   // (d,n)
    const float* Dx  = (const float*)d_in[2];   // (n,d)
    const float* Dy  = (const float*)d_in[3];   // (n,d)
    float* out = (float*)d_out;                 // (B,T,d)

    char* wsb = (char*)d_ws;
    f16*   embf  = (f16*)(wsb + 0);          // 1 MB
    f16*   Ef    = (f16*)(wsb + 1048576);    // 512 KB
    f16*   Dxf   = (f16*)(wsb + 1572864);    // 512 KB
    f16*   Dyf   = (f16*)(wsb + 2097152);    // 512 KB
    f16*   lnvTf = (f16*)(wsb + 2621440);    // 1 MB   [b][j][t]
    f16*   xf    = (f16*)(wsb + 3670016);    // 4 MB   [b][t][n]
    f16*   Wf    = (f16*)(wsb + 7864320);    // 1 MB   [b][t][s]
    f16*   alnf  = (f16*)(wsb + 8912896);    // 1 MB
    f16*   yf    = (f16*)(wsb + 9961472);    // 4 MB
    float* xu    = (float*)(wsb + 14155776); // 8 MB
    float* a     = (float*)(wsb + 22544384); // 2 MB
    float* vpart = (float*)(wsb + 24641536); // 4 MB (2 x ROWS*DD)
    float* Spart = (float*)(wsb + 28835840); // 64 KB (8 x ROWS)
    float* rc    = (float*)(wsb + 28901376); // 8 KB

    // 1. fp16-convert inputs + LN(emb) transposed
    cvtln_kernel<<<1280 + ROWS / 16, 256, 0, stream>>>(
        emb, E, Dx, Dy, embf, Ef, Dxf, Dyf, lnvTf);
    // 2. xu = relu(emb @ Dx^T) + fused row-sum partials   M=2048 N=1024 K=256
    g128_kernel<1><<<dim3(NN / 128, ROWS / 64), 256, 0, stream>>>(
        embf, Dxf, xu, nullptr, nullptr, Spart, NN, DD);
    // 3. normalizer scan (reduce Spart, LDS serial scan, reciprocals)
    cscan_kernel<<<1, 256, 0, stream>>>(Spart, rc);
    // 4. x scan -> fp16
    xscan_kernel<<<BB * (NN / 16), 256, 0, stream>>>(xu, rc, xf);
    // 5. W = mask . (X X^T)  batched  M=N=256 K=1024
    g64_kernel<3><<<dim3(TT / 64, TT / 64, BB), 256, 0, stream>>>(
        xf, xf, nullptr, Wf, TT, NN, NN,
        (long long)TT * NN, (long long)TT * NN, (long long)TT * TT);
    // 6. a = W @ lnv  batched  M=256 N=256 K=256
    g64_kernel<0><<<dim3(DD / 64, TT / 64, BB), 256, 0, stream>>>(
        Wf, lnvTf, a, nullptr, DD, TT, TT,
        (long long)TT * TT, (long long)DD * TT, (long long)TT * DD);
    // 7. aln = LN(a) -> fp16
    ln_kernel<1><<<ROWS / 4, 256, 0, stream>>>(a, nullptr, nullptr, alnf);
    // 8. y = relu(aln @ Dy^T) * x -> fp16   M=2048 N=1024 K=256
    g128_kernel<2><<<dim3(NN / 128, ROWS / 64), 256, 0, stream>>>(
        alnf, Dyf, nullptr, yf, xf, nullptr, NN, DD);
    // 9. vpart[z] = y @ E^T (K-half z)   M=2048 N=256 K=512 x2
    g64_kernel<0><<<dim3(DD / 64, ROWS / 64, 2), 256, 0, stream>>>(
        yf, Ef, vpart, nullptr, DD, NN, 512,
        512LL, 512LL, (long long)ROWS * DD);
    // 10. out = LN(vpart0 + vpart1)
    ln_kernel<2><<<ROWS / 4, 256, 0, stream>>>(
        vpart, vpart + (size_t)ROWS * DD, out, nullptr);
}